// Round 1
// baseline (699.525 us; speedup 1.0000x reference)
//
#include <hip/hip_runtime.h>

#define NEG_SLOPE 0.2f

// ---------------- GEMM: C[n,128] = A[n,128] @ W[128,128] (fp32) ----------------
// Tile: 64 rows x 64 cols per block (blockIdx.y = col half), 256 threads,
// 4x4 outputs/thread. LDS: sA 32KB + sW 32KB = 64KB.
__global__ __launch_bounds__(256) void gemm128x64(const float* __restrict__ A,
                                                  const float* __restrict__ W,
                                                  float* __restrict__ C, int n) {
  __shared__ float sA[64 * 128];
  __shared__ float sW[128 * 64];
  const int t = threadIdx.x;
  const int row0 = blockIdx.x * 64;
  const int col0 = blockIdx.y * 64;
  // load A tile (64x128) as float4
  for (int i = t; i < 2048; i += 256) {
    int r = i >> 5, c4 = i & 31;
    int gr = row0 + r;
    float4 v = make_float4(0.f, 0.f, 0.f, 0.f);
    if (gr < n) v = ((const float4*)(A + (size_t)gr * 128))[c4];
    ((float4*)sA)[i] = v;
  }
  // load W half (128x64) as float4: sW[k][c]
  for (int i = t; i < 2048; i += 256) {
    int k = i >> 4, c4 = i & 15;
    ((float4*)sW)[i] = ((const float4*)(W + (size_t)k * 128 + col0))[c4];
  }
  __syncthreads();
  const int tx = t & 15, ty = t >> 4;   // 16 col-groups x 16 row-groups
  const int c0 = tx * 4, r0 = ty * 4;
  float acc[4][4] = {};
  for (int k = 0; k < 128; k += 4) {
    float4 w0 = *(const float4*)(sW + (k + 0) * 64 + c0);
    float4 w1 = *(const float4*)(sW + (k + 1) * 64 + c0);
    float4 w2 = *(const float4*)(sW + (k + 2) * 64 + c0);
    float4 w3 = *(const float4*)(sW + (k + 3) * 64 + c0);
#pragma unroll
    for (int r = 0; r < 4; ++r) {
      float4 a = *(const float4*)(sA + (r0 + r) * 128 + k);
      acc[r][0] += a.x * w0.x + a.y * w1.x + a.z * w2.x + a.w * w3.x;
      acc[r][1] += a.x * w0.y + a.y * w1.y + a.z * w2.y + a.w * w3.y;
      acc[r][2] += a.x * w0.z + a.y * w1.z + a.z * w2.z + a.w * w3.z;
      acc[r][3] += a.x * w0.w + a.y * w1.w + a.z * w2.w + a.w * w3.w;
    }
  }
#pragma unroll
  for (int r = 0; r < 4; ++r) {
    int gr = row0 + r0 + r;
    if (gr < n) {
      float4 v = make_float4(acc[r][0], acc[r][1], acc[r][2], acc[r][3]);
      *(float4*)(C + (size_t)gr * 128 + col0 + c0) = v;
    }
  }
}

// ---------------- per-node attention logits ----------------
// layer0: thread per (node,head): el/er = dot(feat[n,h,:32], attn[h,:32])
__global__ __launch_bounds__(256) void node_attn4(const float* __restrict__ feat,
    const float* __restrict__ attn_l, const float* __restrict__ attn_r,
    float* __restrict__ el, float* __restrict__ er, int n4) {
  int i = blockIdx.x * 256 + threadIdx.x;
  if (i >= n4) return;
  const int h = i & 3;
  const float* f = feat + (size_t)i * 32;   // (i>>2)*128 + h*32 == i*32
  const float* al = attn_l + h * 32;
  const float* ar = attn_r + h * 32;
  float sl = 0.f, sr = 0.f;
#pragma unroll
  for (int k = 0; k < 32; k += 4) {
    float4 v = *(const float4*)(f + k);
    float4 a = *(const float4*)(al + k);
    float4 b = *(const float4*)(ar + k);
    sl += v.x * a.x + v.y * a.y + v.z * a.z + v.w * a.w;
    sr += v.x * b.x + v.y * b.y + v.z * b.z + v.w * b.w;
  }
  el[i] = sl;
  er[i] = sr;
}

// layer1: thread per node, 128-dot
__global__ __launch_bounds__(256) void node_attn1(const float* __restrict__ feat,
    const float* __restrict__ attn_l, const float* __restrict__ attn_r,
    float* __restrict__ el, float* __restrict__ er, int n) {
  int i = blockIdx.x * 256 + threadIdx.x;
  if (i >= n) return;
  const float* f = feat + (size_t)i * 128;
  float sl = 0.f, sr = 0.f;
#pragma unroll 8
  for (int k = 0; k < 128; k += 4) {
    float4 v = *(const float4*)(f + k);
    float4 a = *(const float4*)(attn_l + k);
    float4 b = *(const float4*)(attn_r + k);
    sl += v.x * a.x + v.y * a.y + v.z * a.z + v.w * a.w;
    sr += v.x * b.x + v.y * b.y + v.z * b.z + v.w * b.w;
  }
  el[i] = sl;
  er[i] = sr;
}

// ---------------- CSR build (graph constant across layers) ----------------
__global__ void hist_kernel(const int* __restrict__ dst, int* __restrict__ deg, int E_) {
  int i = blockIdx.x * 256 + threadIdx.x;
  if (i < E_) atomicAdd(&deg[dst[i]], 1);
}

__global__ __launch_bounds__(1024) void scan_kernel(const int* __restrict__ deg,
    int* __restrict__ rowptr, int* __restrict__ cursor, int n) {
  __shared__ int part[1024];
  const int t = threadIdx.x;
  const int chunk = (n + 1023) >> 10;
  const int b = t * chunk;
  const int e = min(b + chunk, n);
  int s = 0;
  for (int i = b; i < e; ++i) s += deg[i];
  part[t] = s;
  __syncthreads();
  for (int off = 1; off < 1024; off <<= 1) {
    int v = (t >= off) ? part[t - off] : 0;
    __syncthreads();
    part[t] += v;
    __syncthreads();
  }
  int run = (t == 0) ? 0 : part[t - 1];
  for (int i = b; i < e; ++i) {
    rowptr[i] = run;
    cursor[i] = run;
    run += deg[i];
  }
  if (t == 0) rowptr[n] = part[1023];
}

__global__ void scatter_kernel(const int* __restrict__ src, const int* __restrict__ dst,
    int* __restrict__ cursor, int* __restrict__ csr_src, int* __restrict__ csr_eid, int E_) {
  int i = blockIdx.x * 256 + threadIdx.x;
  if (i >= E_) return;
  int p = atomicAdd(&cursor[dst[i]], 1);
  csr_src[p] = src[i];
  csr_eid[p] = i;
}

// ---------------- edge exp + denominator (softmax without max-subtract) ----------------
__global__ void edge_exp4(const int* __restrict__ src, const int* __restrict__ dst,
    const float* __restrict__ el, const float* __restrict__ er,
    float* __restrict__ exp_e, float* __restrict__ denom, int E_) {
  int i = blockIdx.x * 256 + threadIdx.x;
  if (i >= E_) return;
  int s = src[i], d = dst[i];
  float4 l = *(const float4*)(el + (size_t)s * 4);
  float4 r = *(const float4*)(er + (size_t)d * 4);
  float e;
  float4 ex;
  e = l.x + r.x; e = e > 0.f ? e : NEG_SLOPE * e; ex.x = __expf(e);
  e = l.y + r.y; e = e > 0.f ? e : NEG_SLOPE * e; ex.y = __expf(e);
  e = l.z + r.z; e = e > 0.f ? e : NEG_SLOPE * e; ex.z = __expf(e);
  e = l.w + r.w; e = e > 0.f ? e : NEG_SLOPE * e; ex.w = __expf(e);
  *(float4*)(exp_e + (size_t)i * 4) = ex;
  atomicAdd(&denom[(size_t)d * 4 + 0], ex.x);
  atomicAdd(&denom[(size_t)d * 4 + 1], ex.y);
  atomicAdd(&denom[(size_t)d * 4 + 2], ex.z);
  atomicAdd(&denom[(size_t)d * 4 + 3], ex.w);
}

__global__ void edge_exp1(const int* __restrict__ src, const int* __restrict__ dst,
    const float* __restrict__ el, const float* __restrict__ er,
    float* __restrict__ exp_e, float* __restrict__ denom, int E_) {
  int i = blockIdx.x * 256 + threadIdx.x;
  if (i >= E_) return;
  float e = el[src[i]] + er[dst[i]];
  e = e > 0.f ? e : NEG_SLOPE * e;
  float ex = __expf(e);
  exp_e[i] = ex;
  atomicAdd(&denom[dst[i]], ex);
}

// ---------------- aggregation: wave per dst node, gather over CSR ----------------
__global__ __launch_bounds__(256) void aggregate4(const int* __restrict__ rowptr,
    const int* __restrict__ csr_src, const int* __restrict__ csr_eid,
    const float* __restrict__ feat, const float* __restrict__ exp_e,
    const float* __restrict__ denom, const float* __restrict__ bias,
    float* __restrict__ out, int n) {
  int node = blockIdx.x * 4 + (threadIdx.x >> 6);
  if (node >= n) return;
  const int lane = threadIdx.x & 63;
  const int f0 = lane, f1 = lane + 64;
  const int h0 = lane >> 5;      // 0..1
  const int h1 = h0 + 2;         // 2..3
  float d0 = denom[(size_t)node * 4 + h0];
  float d1 = denom[(size_t)node * 4 + h1];
  float inv0 = d0 > 0.f ? 1.f / d0 : 0.f;
  float inv1 = d1 > 0.f ? 1.f / d1 : 0.f;
  float a0 = 0.f, a1 = 0.f;
  const int beg = rowptr[node], end = rowptr[node + 1];
  for (int idx = beg; idx < end; ++idx) {
    int s = csr_src[idx];
    int eid = csr_eid[idx];
    float w0 = exp_e[(size_t)eid * 4 + h0] * inv0;
    float w1 = exp_e[(size_t)eid * 4 + h1] * inv1;
    const float* fr = feat + (size_t)s * 128;
    a0 += fr[f0] * w0;
    a1 += fr[f1] * w1;
  }
  float v0 = a0 + bias[f0];
  v0 = v0 > 0.f ? v0 : __expf(v0) - 1.f;   // ELU
  float v1 = a1 + bias[f1];
  v1 = v1 > 0.f ? v1 : __expf(v1) - 1.f;
  out[(size_t)node * 128 + f0] = v0;
  out[(size_t)node * 128 + f1] = v1;
}

__global__ __launch_bounds__(256) void aggregate1(const int* __restrict__ rowptr,
    const int* __restrict__ csr_src, const int* __restrict__ csr_eid,
    const float* __restrict__ feat, const float* __restrict__ exp_e,
    const float* __restrict__ denom, const float* __restrict__ bias,
    float* __restrict__ out, int n) {
  int node = blockIdx.x * 4 + (threadIdx.x >> 6);
  if (node >= n) return;
  const int lane = threadIdx.x & 63;
  float d = denom[node];
  float inv = d > 0.f ? 1.f / d : 0.f;
  float a0 = 0.f, a1 = 0.f;
  const int beg = rowptr[node], end = rowptr[node + 1];
  for (int idx = beg; idx < end; ++idx) {
    int s = csr_src[idx];
    int eid = csr_eid[idx];
    float w = exp_e[eid] * inv;
    const float* fr = feat + (size_t)s * 128;
    a0 += fr[lane] * w;
    a1 += fr[lane + 64] * w;
  }
  float v0 = a0 + bias[lane];
  v0 = v0 > 0.f ? v0 : __expf(v0) - 1.f;
  float v1 = a1 + bias[lane + 64];
  v1 = v1 > 0.f ? v1 : __expf(v1) - 1.f;
  out[(size_t)node * 128 + lane] = v0;
  out[(size_t)node * 128 + lane + 64] = v1;
}

// ---------------- launch ----------------
extern "C" void kernel_launch(void* const* d_in, const int* in_sizes, int n_in,
                              void* d_out, int out_size, void* d_ws, size_t ws_size,
                              hipStream_t stream) {
  const float* x   = (const float*)d_in[0];
  const int*   src = (const int*)d_in[1];
  const int*   dst = (const int*)d_in[2];
  const float* W0  = (const float*)d_in[3];
  const float* al0 = (const float*)d_in[4];
  const float* ar0 = (const float*)d_in[5];
  const float* b0  = (const float*)d_in[6];
  const float* W1  = (const float*)d_in[7];
  const float* al1 = (const float*)d_in[8];
  const float* ar1 = (const float*)d_in[9];
  const float* b1  = (const float*)d_in[10];
  float* out = (float*)d_out;
  const int n  = in_sizes[0] / 128;
  const int E_ = in_sizes[1];

  char* p = (char*)d_ws;
  auto alloc = [&](size_t bytes) {
    char* r = p;
    p += (bytes + 255) & ~(size_t)255;
    return r;
  };
  float* feat0 = (float*)alloc((size_t)n * 128 * 4);
  float* h0    = (float*)alloc((size_t)n * 128 * 4);
  float* feat1 = (float*)alloc((size_t)n * 128 * 4);
  float* el0   = (float*)alloc((size_t)n * 4 * 4);
  float* er0   = (float*)alloc((size_t)n * 4 * 4);
  float* el1   = (float*)alloc((size_t)n * 4);
  float* er1   = (float*)alloc((size_t)n * 4);
  float* exp0  = (float*)alloc((size_t)E_ * 4 * 4);
  float* exp1  = (float*)alloc((size_t)E_ * 4);
  float* den0  = (float*)alloc((size_t)n * 4 * 4);
  float* den1  = (float*)alloc((size_t)n * 4);
  int* deg     = (int*)alloc((size_t)n * 4);
  int* rowptr  = (int*)alloc((size_t)(n + 1) * 4);
  int* cursor  = (int*)alloc((size_t)n * 4);
  int* csr_src = (int*)alloc((size_t)E_ * 4);
  int* csr_eid = (int*)alloc((size_t)E_ * 4);

  hipMemsetAsync(den0, 0, (size_t)n * 4 * 4, stream);
  hipMemsetAsync(den1, 0, (size_t)n * 4, stream);
  hipMemsetAsync(deg, 0, (size_t)n * 4, stream);

  const int eb = (E_ + 255) / 256;

  // CSR build (graph shared by both layers)
  hist_kernel<<<eb, 256, 0, stream>>>(dst, deg, E_);
  scan_kernel<<<1, 1024, 0, stream>>>(deg, rowptr, cursor, n);
  scatter_kernel<<<eb, 256, 0, stream>>>(src, dst, cursor, csr_src, csr_eid, E_);

  dim3 gg((n + 63) / 64, 2);

  // layer 0
  gemm128x64<<<gg, 256, 0, stream>>>(x, W0, feat0, n);
  node_attn4<<<(n * 4 + 255) / 256, 256, 0, stream>>>(feat0, al0, ar0, el0, er0, n * 4);
  edge_exp4<<<eb, 256, 0, stream>>>(src, dst, el0, er0, exp0, den0, E_);
  aggregate4<<<(n + 3) / 4, 256, 0, stream>>>(rowptr, csr_src, csr_eid, feat0, exp0, den0, b0, h0, n);

  // layer 1
  gemm128x64<<<gg, 256, 0, stream>>>(h0, W1, feat1, n);
  node_attn1<<<(n + 255) / 256, 256, 0, stream>>>(feat1, al1, ar1, el1, er1, n);
  edge_exp1<<<eb, 256, 0, stream>>>(src, dst, el1, er1, exp1, den1, E_);
  aggregate1<<<(n + 3) / 4, 256, 0, stream>>>(rowptr, csr_src, csr_eid, feat1, exp1, den1, b1, out, n);
}

// Round 2
// 481.664 us; speedup vs baseline: 1.4523x; 1.4523x over previous
//
#include <hip/hip_runtime.h>

#define NEG_SLOPE 0.2f

// ---------------- GEMM: C[n,128] = A[n,128] @ W[128,128] (fp32) ----------------
// Tile: 64 rows x 64 cols per block (blockIdx.y = col half), 256 threads,
// 4x4 outputs/thread. LDS: sA 32KB + sW 32KB = 64KB.
__global__ __launch_bounds__(256) void gemm128x64(const float* __restrict__ A,
                                                  const float* __restrict__ W,
                                                  float* __restrict__ C, int n) {
  __shared__ float sA[64 * 128];
  __shared__ float sW[128 * 64];
  const int t = threadIdx.x;
  const int row0 = blockIdx.x * 64;
  const int col0 = blockIdx.y * 64;
  for (int i = t; i < 2048; i += 256) {
    int r = i >> 5, c4 = i & 31;
    int gr = row0 + r;
    float4 v = make_float4(0.f, 0.f, 0.f, 0.f);
    if (gr < n) v = ((const float4*)(A + (size_t)gr * 128))[c4];
    ((float4*)sA)[i] = v;
  }
  for (int i = t; i < 2048; i += 256) {
    int k = i >> 4, c4 = i & 15;
    ((float4*)sW)[i] = ((const float4*)(W + (size_t)k * 128 + col0))[c4];
  }
  __syncthreads();
  const int tx = t & 15, ty = t >> 4;
  const int c0 = tx * 4, r0 = ty * 4;
  float acc[4][4] = {};
  for (int k = 0; k < 128; k += 4) {
    float4 w0 = *(const float4*)(sW + (k + 0) * 64 + c0);
    float4 w1 = *(const float4*)(sW + (k + 1) * 64 + c0);
    float4 w2 = *(const float4*)(sW + (k + 2) * 64 + c0);
    float4 w3 = *(const float4*)(sW + (k + 3) * 64 + c0);
#pragma unroll
    for (int r = 0; r < 4; ++r) {
      float4 a = *(const float4*)(sA + (r0 + r) * 128 + k);
      acc[r][0] += a.x * w0.x + a.y * w1.x + a.z * w2.x + a.w * w3.x;
      acc[r][1] += a.x * w0.y + a.y * w1.y + a.z * w2.y + a.w * w3.y;
      acc[r][2] += a.x * w0.z + a.y * w1.z + a.z * w2.z + a.w * w3.z;
      acc[r][3] += a.x * w0.w + a.y * w1.w + a.z * w2.w + a.w * w3.w;
    }
  }
#pragma unroll
  for (int r = 0; r < 4; ++r) {
    int gr = row0 + r0 + r;
    if (gr < n) {
      float4 v = make_float4(acc[r][0], acc[r][1], acc[r][2], acc[r][3]);
      *(float4*)(C + (size_t)gr * 128 + col0 + c0) = v;
    }
  }
}

// ---------------- per-node attention logits ----------------
__global__ __launch_bounds__(256) void node_attn4(const float* __restrict__ feat,
    const float* __restrict__ attn_l, const float* __restrict__ attn_r,
    float* __restrict__ el, float* __restrict__ er, int n4) {
  int i = blockIdx.x * 256 + threadIdx.x;
  if (i >= n4) return;
  const int h = i & 3;
  const float* f = feat + (size_t)i * 32;
  const float* al = attn_l + h * 32;
  const float* ar = attn_r + h * 32;
  float sl = 0.f, sr = 0.f;
#pragma unroll
  for (int k = 0; k < 32; k += 4) {
    float4 v = *(const float4*)(f + k);
    float4 a = *(const float4*)(al + k);
    float4 b = *(const float4*)(ar + k);
    sl += v.x * a.x + v.y * a.y + v.z * a.z + v.w * a.w;
    sr += v.x * b.x + v.y * b.y + v.z * b.z + v.w * b.w;
  }
  el[i] = sl;
  er[i] = sr;
}

__global__ __launch_bounds__(256) void node_attn1(const float* __restrict__ feat,
    const float* __restrict__ attn_l, const float* __restrict__ attn_r,
    float* __restrict__ el, float* __restrict__ er, int n) {
  int i = blockIdx.x * 256 + threadIdx.x;
  if (i >= n) return;
  const float* f = feat + (size_t)i * 128;
  float sl = 0.f, sr = 0.f;
#pragma unroll 8
  for (int k = 0; k < 128; k += 4) {
    float4 v = *(const float4*)(f + k);
    float4 a = *(const float4*)(attn_l + k);
    float4 b = *(const float4*)(attn_r + k);
    sl += v.x * a.x + v.y * a.y + v.z * a.z + v.w * a.w;
    sr += v.x * b.x + v.y * b.y + v.z * b.z + v.w * b.w;
  }
  el[i] = sl;
  er[i] = sr;
}

// ---------------- CSR build (graph constant across layers) ----------------
__global__ void hist_kernel(const int* __restrict__ dst, int* __restrict__ deg, int E_) {
  int i = blockIdx.x * 256 + threadIdx.x;
  if (i < E_) atomicAdd(&deg[dst[i]], 1);
}

__global__ __launch_bounds__(1024) void scan_kernel(const int* __restrict__ deg,
    int* __restrict__ rowptr, int* __restrict__ cursor, int n) {
  __shared__ int part[1024];
  const int t = threadIdx.x;
  const int chunk = (n + 1023) >> 10;
  const int b = t * chunk;
  const int e = min(b + chunk, n);
  int s = 0;
  for (int i = b; i < e; ++i) s += deg[i];
  part[t] = s;
  __syncthreads();
  for (int off = 1; off < 1024; off <<= 1) {
    int v = (t >= off) ? part[t - off] : 0;
    __syncthreads();
    part[t] += v;
    __syncthreads();
  }
  int run = (t == 0) ? 0 : part[t - 1];
  for (int i = b; i < e; ++i) {
    rowptr[i] = run;
    cursor[i] = run;
    run += deg[i];
  }
  if (t == 0) rowptr[n] = part[1023];
}

__global__ void scatter_kernel(const int* __restrict__ src, const int* __restrict__ dst,
    int* __restrict__ cursor, int* __restrict__ csr_src, int E_) {
  int i = blockIdx.x * 256 + threadIdx.x;
  if (i >= E_) return;
  int p = atomicAdd(&cursor[dst[i]], 1);
  csr_src[p] = src[i];
}

// ---------------- fused edge-softmax + aggregation: wave per dst node ----------------
// alpha-weighted sum is linear: out = (sum_e w_e * feat[src_e]) / (sum_e w_e),
// w_e = exp(leakyrelu(el[src]+er[dst])) -- no max-subtract needed (|e| small),
// no atomics, no exp_e/denom materialization.
__global__ __launch_bounds__(256) void aggregate4(const int* __restrict__ rowptr,
    const int* __restrict__ csr_src, const float* __restrict__ feat,
    const float* __restrict__ el, const float* __restrict__ er,
    const float* __restrict__ bias, float* __restrict__ out, int n) {
  int node = blockIdx.x * 4 + (threadIdx.x >> 6);
  if (node >= n) return;
  const int lane = threadIdx.x & 63;
  const int f0 = lane, f1 = lane + 64;
  const int h0 = lane >> 5;      // 0..1
  const int h1 = h0 + 2;         // 2..3
  const float er0 = er[(size_t)node * 4 + h0];
  const float er1 = er[(size_t)node * 4 + h1];
  float a0 = 0.f, a1 = 0.f, d0 = 0.f, d1 = 0.f;
  const int beg = rowptr[node], end = rowptr[node + 1];
  for (int idx = beg; idx < end; ++idx) {
    int s = csr_src[idx];
    float e0 = el[(size_t)s * 4 + h0] + er0;
    e0 = e0 > 0.f ? e0 : NEG_SLOPE * e0;
    float w0 = __expf(e0);
    float e1 = el[(size_t)s * 4 + h1] + er1;
    e1 = e1 > 0.f ? e1 : NEG_SLOPE * e1;
    float w1 = __expf(e1);
    const float* fr = feat + (size_t)s * 128;
    a0 += fr[f0] * w0;
    a1 += fr[f1] * w1;
    d0 += w0;
    d1 += w1;
  }
  float inv0 = d0 > 0.f ? 1.f / d0 : 0.f;
  float inv1 = d1 > 0.f ? 1.f / d1 : 0.f;
  float v0 = a0 * inv0 + bias[f0];
  v0 = v0 > 0.f ? v0 : __expf(v0) - 1.f;   // ELU
  float v1 = a1 * inv1 + bias[f1];
  v1 = v1 > 0.f ? v1 : __expf(v1) - 1.f;
  out[(size_t)node * 128 + f0] = v0;
  out[(size_t)node * 128 + f1] = v1;
}

__global__ __launch_bounds__(256) void aggregate1(const int* __restrict__ rowptr,
    const int* __restrict__ csr_src, const float* __restrict__ feat,
    const float* __restrict__ el, const float* __restrict__ er,
    const float* __restrict__ bias, float* __restrict__ out, int n) {
  int node = blockIdx.x * 4 + (threadIdx.x >> 6);
  if (node >= n) return;
  const int lane = threadIdx.x & 63;
  const float erv = er[node];
  float a0 = 0.f, a1 = 0.f, d = 0.f;
  const int beg = rowptr[node], end = rowptr[node + 1];
  for (int idx = beg; idx < end; ++idx) {
    int s = csr_src[idx];
    float e = el[s] + erv;
    e = e > 0.f ? e : NEG_SLOPE * e;
    float w = __expf(e);
    const float* fr = feat + (size_t)s * 128;
    a0 += fr[lane] * w;
    a1 += fr[lane + 64] * w;
    d += w;
  }
  float inv = d > 0.f ? 1.f / d : 0.f;
  float v0 = a0 * inv + bias[lane];
  v0 = v0 > 0.f ? v0 : __expf(v0) - 1.f;
  float v1 = a1 * inv + bias[lane + 64];
  v1 = v1 > 0.f ? v1 : __expf(v1) - 1.f;
  out[(size_t)node * 128 + lane] = v0;
  out[(size_t)node * 128 + lane + 64] = v1;
}

// ---------------- launch ----------------
extern "C" void kernel_launch(void* const* d_in, const int* in_sizes, int n_in,
                              void* d_out, int out_size, void* d_ws, size_t ws_size,
                              hipStream_t stream) {
  const float* x   = (const float*)d_in[0];
  const int*   src = (const int*)d_in[1];
  const int*   dst = (const int*)d_in[2];
  const float* W0  = (const float*)d_in[3];
  const float* al0 = (const float*)d_in[4];
  const float* ar0 = (const float*)d_in[5];
  const float* b0  = (const float*)d_in[6];
  const float* W1  = (const float*)d_in[7];
  const float* al1 = (const float*)d_in[8];
  const float* ar1 = (const float*)d_in[9];
  const float* b1  = (const float*)d_in[10];
  float* out = (float*)d_out;
  const int n  = in_sizes[0] / 128;
  const int E_ = in_sizes[1];

  char* p = (char*)d_ws;
  auto alloc = [&](size_t bytes) {
    char* r = p;
    p += (bytes + 255) & ~(size_t)255;
    return r;
  };
  float* feat0 = (float*)alloc((size_t)n * 128 * 4);
  float* h0    = (float*)alloc((size_t)n * 128 * 4);
  float* feat1 = (float*)alloc((size_t)n * 128 * 4);
  float* el0   = (float*)alloc((size_t)n * 4 * 4);
  float* er0   = (float*)alloc((size_t)n * 4 * 4);
  float* el1   = (float*)alloc((size_t)n * 4);
  float* er1   = (float*)alloc((size_t)n * 4);
  int* deg     = (int*)alloc((size_t)n * 4);
  int* rowptr  = (int*)alloc((size_t)(n + 1) * 4);
  int* cursor  = (int*)alloc((size_t)n * 4);
  int* csr_src = (int*)alloc((size_t)E_ * 4);

  hipMemsetAsync(deg, 0, (size_t)n * 4, stream);

  const int eb = (E_ + 255) / 256;

  // CSR build (graph shared by both layers)
  hist_kernel<<<eb, 256, 0, stream>>>(dst, deg, E_);
  scan_kernel<<<1, 1024, 0, stream>>>(deg, rowptr, cursor, n);
  scatter_kernel<<<eb, 256, 0, stream>>>(src, dst, cursor, csr_src, E_);

  dim3 gg((n + 63) / 64, 2);

  // layer 0
  gemm128x64<<<gg, 256, 0, stream>>>(x, W0, feat0, n);
  node_attn4<<<(n * 4 + 255) / 256, 256, 0, stream>>>(feat0, al0, ar0, el0, er0, n * 4);
  aggregate4<<<(n + 3) / 4, 256, 0, stream>>>(rowptr, csr_src, feat0, el0, er0, b0, h0, n);

  // layer 1
  gemm128x64<<<gg, 256, 0, stream>>>(h0, W1, feat1, n);
  node_attn1<<<(n + 255) / 256, 256, 0, stream>>>(feat1, al1, ar1, el1, er1, n);
  aggregate1<<<(n + 3) / 4, 256, 0, stream>>>(rowptr, csr_src, feat1, el1, er1, b1, out, n);
}

// Round 3
// 379.782 us; speedup vs baseline: 1.8419x; 1.2683x over previous
//
#include <hip/hip_runtime.h>

#define NEG_SLOPE 0.2f

// ---------------- GEMM: C[n,128] = A[n,128] @ W[128,128] (fp32) ----------------
__global__ __launch_bounds__(256) void gemm128x64(const float* __restrict__ A,
                                                  const float* __restrict__ W,
                                                  float* __restrict__ C, int n) {
  __shared__ float sA[64 * 128];
  __shared__ float sW[128 * 64];
  const int t = threadIdx.x;
  const int row0 = blockIdx.x * 64;
  const int col0 = blockIdx.y * 64;
  for (int i = t; i < 2048; i += 256) {
    int r = i >> 5, c4 = i & 31;
    int gr = row0 + r;
    float4 v = make_float4(0.f, 0.f, 0.f, 0.f);
    if (gr < n) v = ((const float4*)(A + (size_t)gr * 128))[c4];
    ((float4*)sA)[i] = v;
  }
  for (int i = t; i < 2048; i += 256) {
    int k = i >> 4, c4 = i & 15;
    ((float4*)sW)[i] = ((const float4*)(W + (size_t)k * 128 + col0))[c4];
  }
  __syncthreads();
  const int tx = t & 15, ty = t >> 4;
  const int c0 = tx * 4, r0 = ty * 4;
  float acc[4][4] = {};
  for (int k = 0; k < 128; k += 4) {
    float4 w0 = *(const float4*)(sW + (k + 0) * 64 + c0);
    float4 w1 = *(const float4*)(sW + (k + 1) * 64 + c0);
    float4 w2 = *(const float4*)(sW + (k + 2) * 64 + c0);
    float4 w3 = *(const float4*)(sW + (k + 3) * 64 + c0);
#pragma unroll
    for (int r = 0; r < 4; ++r) {
      float4 a = *(const float4*)(sA + (r0 + r) * 128 + k);
      acc[r][0] += a.x * w0.x + a.y * w1.x + a.z * w2.x + a.w * w3.x;
      acc[r][1] += a.x * w0.y + a.y * w1.y + a.z * w2.y + a.w * w3.y;
      acc[r][2] += a.x * w0.z + a.y * w1.z + a.z * w2.z + a.w * w3.z;
      acc[r][3] += a.x * w0.w + a.y * w1.w + a.z * w2.w + a.w * w3.w;
    }
  }
#pragma unroll
  for (int r = 0; r < 4; ++r) {
    int gr = row0 + r0 + r;
    if (gr < n) {
      float4 v = make_float4(acc[r][0], acc[r][1], acc[r][2], acc[r][3]);
      *(float4*)(C + (size_t)gr * 128 + col0 + c0) = v;
    }
  }
}

// ---------------- per-node attention logits ----------------
__global__ __launch_bounds__(256) void node_attn4(const float* __restrict__ feat,
    const float* __restrict__ attn_l, const float* __restrict__ attn_r,
    float* __restrict__ el, float* __restrict__ er, int n4) {
  int i = blockIdx.x * 256 + threadIdx.x;
  if (i >= n4) return;
  const int h = i & 3;
  const float* f = feat + (size_t)i * 32;
  const float* al = attn_l + h * 32;
  const float* ar = attn_r + h * 32;
  float sl = 0.f, sr = 0.f;
#pragma unroll
  for (int k = 0; k < 32; k += 4) {
    float4 v = *(const float4*)(f + k);
    float4 a = *(const float4*)(al + k);
    float4 b = *(const float4*)(ar + k);
    sl += v.x * a.x + v.y * a.y + v.z * a.z + v.w * a.w;
    sr += v.x * b.x + v.y * b.y + v.z * b.z + v.w * b.w;
  }
  el[i] = sl;
  er[i] = sr;
}

__global__ __launch_bounds__(256) void node_attn1(const float* __restrict__ feat,
    const float* __restrict__ attn_l, const float* __restrict__ attn_r,
    float* __restrict__ el, float* __restrict__ er, int n) {
  int i = blockIdx.x * 256 + threadIdx.x;
  if (i >= n) return;
  const float* f = feat + (size_t)i * 128;
  float sl = 0.f, sr = 0.f;
#pragma unroll 8
  for (int k = 0; k < 128; k += 4) {
    float4 v = *(const float4*)(f + k);
    float4 a = *(const float4*)(attn_l + k);
    float4 b = *(const float4*)(attn_r + k);
    sl += v.x * a.x + v.y * a.y + v.z * a.z + v.w * a.w;
    sr += v.x * b.x + v.y * b.y + v.z * b.z + v.w * b.w;
  }
  el[i] = sl;
  er[i] = sr;
}

// ---------------- CSR build (graph constant across layers) ----------------
__global__ void hist_kernel(const int* __restrict__ dst, int* __restrict__ deg, int E_) {
  int i = blockIdx.x * 256 + threadIdx.x;
  if (i < E_) atomicAdd(&deg[dst[i]], 1);
}

// device-wide exclusive scan of deg[0..n) in 3 parallel phases
__global__ __launch_bounds__(256) void block_sum_kernel(const int* __restrict__ deg,
    int* __restrict__ blockSums, int n) {
  __shared__ int red[256];
  const int t = threadIdx.x;
  int i = blockIdx.x * 256 + t;
  red[t] = (i < n) ? deg[i] : 0;
  __syncthreads();
  for (int off = 128; off > 0; off >>= 1) {
    if (t < off) red[t] += red[t + off];
    __syncthreads();
  }
  if (t == 0) blockSums[blockIdx.x] = red[0];
}

__global__ __launch_bounds__(1024) void scan_blocks_kernel(const int* __restrict__ blockSums,
    int* __restrict__ blockOffs, int* __restrict__ rowptr, int nb, int n) {
  __shared__ int s[1024];
  const int t = threadIdx.x;
  int v = (t < nb) ? blockSums[t] : 0;
  s[t] = v;
  __syncthreads();
  for (int off = 1; off < 1024; off <<= 1) {
    int u = (t >= off) ? s[t - off] : 0;
    __syncthreads();
    s[t] += u;
    __syncthreads();
  }
  if (t < nb) blockOffs[t] = s[t] - v;           // exclusive
  if (t == nb - 1) rowptr[n] = s[t];             // total
}

__global__ __launch_bounds__(256) void scan_apply_kernel(const int* __restrict__ deg,
    const int* __restrict__ blockOffs, int* __restrict__ rowptr,
    int* __restrict__ cursor, int n) {
  __shared__ int s[256];
  const int t = threadIdx.x;
  int i = blockIdx.x * 256 + t;
  int v = (i < n) ? deg[i] : 0;
  s[t] = v;
  __syncthreads();
  for (int off = 1; off < 256; off <<= 1) {
    int u = (t >= off) ? s[t - off] : 0;
    __syncthreads();
    s[t] += u;
    __syncthreads();
  }
  if (i < n) {
    int excl = s[t] - v + blockOffs[blockIdx.x];
    rowptr[i] = excl;
    cursor[i] = excl;
  }
}

__global__ void scatter_kernel(const int* __restrict__ src, const int* __restrict__ dst,
    int* __restrict__ cursor, int* __restrict__ csr_src, int E_) {
  int i = blockIdx.x * 256 + threadIdx.x;
  if (i >= E_) return;
  int p = atomicAdd(&cursor[dst[i]], 1);
  csr_src[p] = src[i];
}

// ---------------- fused edge-softmax + aggregation: wave per dst node ----------------
__global__ __launch_bounds__(256) void aggregate4(const int* __restrict__ rowptr,
    const int* __restrict__ csr_src, const float* __restrict__ feat,
    const float* __restrict__ el, const float* __restrict__ er,
    const float* __restrict__ bias, float* __restrict__ out, int n) {
  int node = blockIdx.x * 4 + (threadIdx.x >> 6);
  if (node >= n) return;
  const int lane = threadIdx.x & 63;
  const int f0 = lane, f1 = lane + 64;
  const int h0 = lane >> 5;      // 0..1
  const int h1 = h0 + 2;         // 2..3
  const float er0 = er[(size_t)node * 4 + h0];
  const float er1 = er[(size_t)node * 4 + h1];
  float a0 = 0.f, a1 = 0.f, d0 = 0.f, d1 = 0.f;
  const int beg = rowptr[node], end = rowptr[node + 1];
  for (int idx = beg; idx < end; ++idx) {
    int s = csr_src[idx];
    float e0 = el[(size_t)s * 4 + h0] + er0;
    e0 = e0 > 0.f ? e0 : NEG_SLOPE * e0;
    float w0 = __expf(e0);
    float e1 = el[(size_t)s * 4 + h1] + er1;
    e1 = e1 > 0.f ? e1 : NEG_SLOPE * e1;
    float w1 = __expf(e1);
    const float* fr = feat + (size_t)s * 128;
    a0 += fr[f0] * w0;
    a1 += fr[f1] * w1;
    d0 += w0;
    d1 += w1;
  }
  float inv0 = d0 > 0.f ? 1.f / d0 : 0.f;
  float inv1 = d1 > 0.f ? 1.f / d1 : 0.f;
  float v0 = a0 * inv0 + bias[f0];
  v0 = v0 > 0.f ? v0 : __expf(v0) - 1.f;   // ELU
  float v1 = a1 * inv1 + bias[f1];
  v1 = v1 > 0.f ? v1 : __expf(v1) - 1.f;
  out[(size_t)node * 128 + f0] = v0;
  out[(size_t)node * 128 + f1] = v1;
}

__global__ __launch_bounds__(256) void aggregate1(const int* __restrict__ rowptr,
    const int* __restrict__ csr_src, const float* __restrict__ feat,
    const float* __restrict__ el, const float* __restrict__ er,
    const float* __restrict__ bias, float* __restrict__ out, int n) {
  int node = blockIdx.x * 4 + (threadIdx.x >> 6);
  if (node >= n) return;
  const int lane = threadIdx.x & 63;
  const float erv = er[node];
  float a0 = 0.f, a1 = 0.f, d = 0.f;
  const int beg = rowptr[node], end = rowptr[node + 1];
  for (int idx = beg; idx < end; ++idx) {
    int s = csr_src[idx];
    float e = el[s] + erv;
    e = e > 0.f ? e : NEG_SLOPE * e;
    float w = __expf(e);
    const float* fr = feat + (size_t)s * 128;
    a0 += fr[lane] * w;
    a1 += fr[lane + 64] * w;
    d += w;
  }
  float inv = d > 0.f ? 1.f / d : 0.f;
  float v0 = a0 * inv + bias[lane];
  v0 = v0 > 0.f ? v0 : __expf(v0) - 1.f;
  float v1 = a1 * inv + bias[lane + 64];
  v1 = v1 > 0.f ? v1 : __expf(v1) - 1.f;
  out[(size_t)node * 128 + lane] = v0;
  out[(size_t)node * 128 + lane + 64] = v1;
}

// ---------------- launch ----------------
extern "C" void kernel_launch(void* const* d_in, const int* in_sizes, int n_in,
                              void* d_out, int out_size, void* d_ws, size_t ws_size,
                              hipStream_t stream) {
  const float* x   = (const float*)d_in[0];
  const int*   src = (const int*)d_in[1];
  const int*   dst = (const int*)d_in[2];
  const float* W0  = (const float*)d_in[3];
  const float* al0 = (const float*)d_in[4];
  const float* ar0 = (const float*)d_in[5];
  const float* b0  = (const float*)d_in[6];
  const float* W1  = (const float*)d_in[7];
  const float* al1 = (const float*)d_in[8];
  const float* ar1 = (const float*)d_in[9];
  const float* b1  = (const float*)d_in[10];
  float* out = (float*)d_out;
  const int n  = in_sizes[0] / 128;
  const int E_ = in_sizes[1];

  char* p = (char*)d_ws;
  auto alloc = [&](size_t bytes) {
    char* r = p;
    p += (bytes + 255) & ~(size_t)255;
    return r;
  };
  float* feat0 = (float*)alloc((size_t)n * 128 * 4);
  float* h0    = (float*)alloc((size_t)n * 128 * 4);
  float* feat1 = (float*)alloc((size_t)n * 128 * 4);
  float* el0   = (float*)alloc((size_t)n * 4 * 4);
  float* er0   = (float*)alloc((size_t)n * 4 * 4);
  float* el1   = (float*)alloc((size_t)n * 4);
  float* er1   = (float*)alloc((size_t)n * 4);
  int* deg     = (int*)alloc((size_t)n * 4);
  int* rowptr  = (int*)alloc((size_t)(n + 1) * 4);
  int* cursor  = (int*)alloc((size_t)n * 4);
  int* csr_src = (int*)alloc((size_t)E_ * 4);
  const int nb = (n + 255) / 256;
  int* blockSums = (int*)alloc((size_t)nb * 4);
  int* blockOffs = (int*)alloc((size_t)nb * 4);

  hipMemsetAsync(deg, 0, (size_t)n * 4, stream);

  const int eb = (E_ + 255) / 256;

  // CSR build (graph shared by both layers)
  hist_kernel<<<eb, 256, 0, stream>>>(dst, deg, E_);
  block_sum_kernel<<<nb, 256, 0, stream>>>(deg, blockSums, n);
  scan_blocks_kernel<<<1, 1024, 0, stream>>>(blockSums, blockOffs, rowptr, nb, n);
  scan_apply_kernel<<<nb, 256, 0, stream>>>(deg, blockOffs, rowptr, cursor, n);
  scatter_kernel<<<eb, 256, 0, stream>>>(src, dst, cursor, csr_src, E_);

  dim3 gg((n + 63) / 64, 2);

  // layer 0
  gemm128x64<<<gg, 256, 0, stream>>>(x, W0, feat0, n);
  node_attn4<<<(n * 4 + 255) / 256, 256, 0, stream>>>(feat0, al0, ar0, el0, er0, n * 4);
  aggregate4<<<(n + 3) / 4, 256, 0, stream>>>(rowptr, csr_src, feat0, el0, er0, b0, h0, n);

  // layer 1
  gemm128x64<<<gg, 256, 0, stream>>>(h0, W1, feat1, n);
  node_attn1<<<(n + 255) / 256, 256, 0, stream>>>(feat1, al1, ar1, el1, er1, n);
  aggregate1<<<(n + 3) / 4, 256, 0, stream>>>(rowptr, csr_src, feat1, el1, er1, b1, out, n);
}

// Round 4
// 364.393 us; speedup vs baseline: 1.9197x; 1.0422x over previous
//
#include <hip/hip_runtime.h>

#define NEG_SLOPE 0.2f

__device__ inline ushort bf16rne(float f) {
  uint u = __float_as_uint(f);
  u += 0x7fff + ((u >> 16) & 1);
  return (ushort)(u >> 16);
}

// ---------------- GEMM: C[n,128] = A[n,128] @ W[128,128] (fp32 + bf16 copy) --------
__global__ __launch_bounds__(256) void gemm128x64(const float* __restrict__ A,
                                                  const float* __restrict__ W,
                                                  float* __restrict__ C,
                                                  ushort* __restrict__ Cb, int n) {
  __shared__ float sA[64 * 128];
  __shared__ float sW[128 * 64];
  const int t = threadIdx.x;
  const int row0 = blockIdx.x * 64;
  const int col0 = blockIdx.y * 64;
  for (int i = t; i < 2048; i += 256) {
    int r = i >> 5, c4 = i & 31;
    int gr = row0 + r;
    float4 v = make_float4(0.f, 0.f, 0.f, 0.f);
    if (gr < n) v = ((const float4*)(A + (size_t)gr * 128))[c4];
    ((float4*)sA)[i] = v;
  }
  for (int i = t; i < 2048; i += 256) {
    int k = i >> 4, c4 = i & 15;
    ((float4*)sW)[i] = ((const float4*)(W + (size_t)k * 128 + col0))[c4];
  }
  __syncthreads();
  const int tx = t & 15, ty = t >> 4;
  const int c0 = tx * 4, r0 = ty * 4;
  float acc[4][4] = {};
  for (int k = 0; k < 128; k += 4) {
    float4 w0 = *(const float4*)(sW + (k + 0) * 64 + c0);
    float4 w1 = *(const float4*)(sW + (k + 1) * 64 + c0);
    float4 w2 = *(const float4*)(sW + (k + 2) * 64 + c0);
    float4 w3 = *(const float4*)(sW + (k + 3) * 64 + c0);
#pragma unroll
    for (int r = 0; r < 4; ++r) {
      float4 a = *(const float4*)(sA + (r0 + r) * 128 + k);
      acc[r][0] += a.x * w0.x + a.y * w1.x + a.z * w2.x + a.w * w3.x;
      acc[r][1] += a.x * w0.y + a.y * w1.y + a.z * w2.y + a.w * w3.y;
      acc[r][2] += a.x * w0.z + a.y * w1.z + a.z * w2.z + a.w * w3.z;
      acc[r][3] += a.x * w0.w + a.y * w1.w + a.z * w2.w + a.w * w3.w;
    }
  }
#pragma unroll
  for (int r = 0; r < 4; ++r) {
    int gr = row0 + r0 + r;
    if (gr < n) {
      float4 v = make_float4(acc[r][0], acc[r][1], acc[r][2], acc[r][3]);
      *(float4*)(C + (size_t)gr * 128 + col0 + c0) = v;
      ushort4 b;
      b.x = bf16rne(v.x); b.y = bf16rne(v.y);
      b.z = bf16rne(v.z); b.w = bf16rne(v.w);
      *(ushort4*)(Cb + (size_t)gr * 128 + col0 + c0) = b;
    }
  }
}

// ---------------- per-node attention logits (from fp32 feat) ----------------
__global__ __launch_bounds__(256) void node_attn4(const float* __restrict__ feat,
    const float* __restrict__ attn_l, const float* __restrict__ attn_r,
    float* __restrict__ el, float* __restrict__ er, int n4) {
  int i = blockIdx.x * 256 + threadIdx.x;
  if (i >= n4) return;
  const int h = i & 3;
  const float* f = feat + (size_t)i * 32;
  const float* al = attn_l + h * 32;
  const float* ar = attn_r + h * 32;
  float sl = 0.f, sr = 0.f;
#pragma unroll
  for (int k = 0; k < 32; k += 4) {
    float4 v = *(const float4*)(f + k);
    float4 a = *(const float4*)(al + k);
    float4 b = *(const float4*)(ar + k);
    sl += v.x * a.x + v.y * a.y + v.z * a.z + v.w * a.w;
    sr += v.x * b.x + v.y * b.y + v.z * b.z + v.w * b.w;
  }
  el[i] = sl;
  er[i] = sr;
}

__global__ __launch_bounds__(256) void node_attn1(const float* __restrict__ feat,
    const float* __restrict__ attn_l, const float* __restrict__ attn_r,
    float* __restrict__ el, float* __restrict__ er, int n) {
  int i = blockIdx.x * 256 + threadIdx.x;
  if (i >= n) return;
  const float* f = feat + (size_t)i * 128;
  float sl = 0.f, sr = 0.f;
#pragma unroll 8
  for (int k = 0; k < 128; k += 4) {
    float4 v = *(const float4*)(f + k);
    float4 a = *(const float4*)(attn_l + k);
    float4 b = *(const float4*)(attn_r + k);
    sl += v.x * a.x + v.y * a.y + v.z * a.z + v.w * a.w;
    sr += v.x * b.x + v.y * b.y + v.z * b.z + v.w * b.w;
  }
  el[i] = sl;
  er[i] = sr;
}

// ---------------- CSR build ----------------
__global__ void hist_kernel(const int* __restrict__ dst, int* __restrict__ deg, int E_) {
  int i = blockIdx.x * 256 + threadIdx.x;
  if (i < E_) atomicAdd(&deg[dst[i]], 1);
}

__global__ __launch_bounds__(256) void block_sum_kernel(const int* __restrict__ deg,
    int* __restrict__ blockSums, int n) {
  __shared__ int red[256];
  const int t = threadIdx.x;
  int i = blockIdx.x * 256 + t;
  red[t] = (i < n) ? deg[i] : 0;
  __syncthreads();
  for (int off = 128; off > 0; off >>= 1) {
    if (t < off) red[t] += red[t + off];
    __syncthreads();
  }
  if (t == 0) blockSums[blockIdx.x] = red[0];
}

__global__ __launch_bounds__(1024) void scan_blocks_kernel(const int* __restrict__ blockSums,
    int* __restrict__ blockOffs, int* __restrict__ rowptr, int nb, int n) {
  __shared__ int s[1024];
  const int t = threadIdx.x;
  int v = (t < nb) ? blockSums[t] : 0;
  s[t] = v;
  __syncthreads();
  for (int off = 1; off < 1024; off <<= 1) {
    int u = (t >= off) ? s[t - off] : 0;
    __syncthreads();
    s[t] += u;
    __syncthreads();
  }
  if (t < nb) blockOffs[t] = s[t] - v;
  if (t == nb - 1) rowptr[n] = s[t];
}

__global__ __launch_bounds__(256) void scan_apply_kernel(const int* __restrict__ deg,
    const int* __restrict__ blockOffs, int* __restrict__ rowptr,
    int* __restrict__ cursor, int n) {
  __shared__ int s[256];
  const int t = threadIdx.x;
  int i = blockIdx.x * 256 + t;
  int v = (i < n) ? deg[i] : 0;
  s[t] = v;
  __syncthreads();
  for (int off = 1; off < 256; off <<= 1) {
    int u = (t >= off) ? s[t - off] : 0;
    __syncthreads();
    s[t] += u;
    __syncthreads();
  }
  if (i < n) {
    int excl = s[t] - v + blockOffs[blockIdx.x];
    rowptr[i] = excl;
    cursor[i] = excl;
  }
}

__global__ void scatter_kernel(const int* __restrict__ src, const int* __restrict__ dst,
    int* __restrict__ cursor, int* __restrict__ csr_src, int E_) {
  int i = blockIdx.x * 256 + threadIdx.x;
  if (i >= E_) return;
  int p = atomicAdd(&cursor[dst[i]], 1);
  csr_src[p] = src[i];
}

// ---------------- fused edge-softmax + aggregation (bf16 gather) ----------------
// wave per dst node; lane owns features 2l,2l+1 (head = lane>>4);
// one ushort2 (4B) load per edge per lane = whole 256B bf16 row per wave.
__global__ __launch_bounds__(256) void aggregate4(const int* __restrict__ rowptr,
    const int* __restrict__ csr_src, const ushort* __restrict__ featb,
    const float* __restrict__ el, const float* __restrict__ er,
    const float* __restrict__ bias, float* __restrict__ out, int n) {
  int node = blockIdx.x * 4 + (threadIdx.x >> 6);
  if (node >= n) return;
  const int lane = threadIdx.x & 63;
  const int f0 = lane * 2;
  const int h = lane >> 4;                 // (2*lane)>>5
  const float erh = er[(size_t)node * 4 + h];
  float a0 = 0.f, a1 = 0.f, d = 0.f;
  const int beg = rowptr[node], end = rowptr[node + 1];
  for (int idx = beg; idx < end; ++idx) {
    int s = csr_src[idx];
    float e = el[(size_t)s * 4 + h] + erh;
    e = e > 0.f ? e : NEG_SLOPE * e;
    float w = __expf(e);
    uint v = *(const uint*)(featb + (size_t)s * 128 + f0);
    float x0 = __uint_as_float(v << 16);
    float x1 = __uint_as_float(v & 0xffff0000u);
    a0 += x0 * w;
    a1 += x1 * w;
    d += w;
  }
  float inv = d > 0.f ? 1.f / d : 0.f;
  float v0 = a0 * inv + bias[f0];
  v0 = v0 > 0.f ? v0 : __expf(v0) - 1.f;   // ELU
  float v1 = a1 * inv + bias[f0 + 1];
  v1 = v1 > 0.f ? v1 : __expf(v1) - 1.f;
  *(float2*)(out + (size_t)node * 128 + f0) = make_float2(v0, v1);
}

__global__ __launch_bounds__(256) void aggregate1(const int* __restrict__ rowptr,
    const int* __restrict__ csr_src, const ushort* __restrict__ featb,
    const float* __restrict__ el, const float* __restrict__ er,
    const float* __restrict__ bias, float* __restrict__ out, int n) {
  int node = blockIdx.x * 4 + (threadIdx.x >> 6);
  if (node >= n) return;
  const int lane = threadIdx.x & 63;
  const int f0 = lane * 2;
  const float erv = er[node];
  float a0 = 0.f, a1 = 0.f, d = 0.f;
  const int beg = rowptr[node], end = rowptr[node + 1];
  for (int idx = beg; idx < end; ++idx) {
    int s = csr_src[idx];
    float e = el[s] + erv;
    e = e > 0.f ? e : NEG_SLOPE * e;
    float w = __expf(e);
    uint v = *(const uint*)(featb + (size_t)s * 128 + f0);
    float x0 = __uint_as_float(v << 16);
    float x1 = __uint_as_float(v & 0xffff0000u);
    a0 += x0 * w;
    a1 += x1 * w;
    d += w;
  }
  float inv = d > 0.f ? 1.f / d : 0.f;
  float v0 = a0 * inv + bias[f0];
  v0 = v0 > 0.f ? v0 : __expf(v0) - 1.f;
  float v1 = a1 * inv + bias[f0 + 1];
  v1 = v1 > 0.f ? v1 : __expf(v1) - 1.f;
  *(float2*)(out + (size_t)node * 128 + f0) = make_float2(v0, v1);
}

// ---------------- launch ----------------
extern "C" void kernel_launch(void* const* d_in, const int* in_sizes, int n_in,
                              void* d_out, int out_size, void* d_ws, size_t ws_size,
                              hipStream_t stream) {
  const float* x   = (const float*)d_in[0];
  const int*   src = (const int*)d_in[1];
  const int*   dst = (const int*)d_in[2];
  const float* W0  = (const float*)d_in[3];
  const float* al0 = (const float*)d_in[4];
  const float* ar0 = (const float*)d_in[5];
  const float* b0  = (const float*)d_in[6];
  const float* W1  = (const float*)d_in[7];
  const float* al1 = (const float*)d_in[8];
  const float* ar1 = (const float*)d_in[9];
  const float* b1  = (const float*)d_in[10];
  float* out = (float*)d_out;
  const int n  = in_sizes[0] / 128;
  const int E_ = in_sizes[1];

  char* p = (char*)d_ws;
  auto alloc = [&](size_t bytes) {
    char* r = p;
    p += (bytes + 255) & ~(size_t)255;
    return r;
  };
  float*  feat0  = (float*)alloc((size_t)n * 128 * 4);
  ushort* feat0b = (ushort*)alloc((size_t)n * 128 * 2);
  float*  h0     = (float*)alloc((size_t)n * 128 * 4);
  float*  feat1  = (float*)alloc((size_t)n * 128 * 4);
  ushort* feat1b = (ushort*)alloc((size_t)n * 128 * 2);
  float* el0   = (float*)alloc((size_t)n * 4 * 4);
  float* er0   = (float*)alloc((size_t)n * 4 * 4);
  float* el1   = (float*)alloc((size_t)n * 4);
  float* er1   = (float*)alloc((size_t)n * 4);
  int* deg     = (int*)alloc((size_t)n * 4);
  int* rowptr  = (int*)alloc((size_t)(n + 1) * 4);
  int* cursor  = (int*)alloc((size_t)n * 4);
  int* csr_src = (int*)alloc((size_t)E_ * 4);
  const int nb = (n + 255) / 256;
  int* blockSums = (int*)alloc((size_t)nb * 4);
  int* blockOffs = (int*)alloc((size_t)nb * 4);

  hipMemsetAsync(deg, 0, (size_t)n * 4, stream);

  const int eb = (E_ + 255) / 256;

  // CSR build (graph shared by both layers)
  hist_kernel<<<eb, 256, 0, stream>>>(dst, deg, E_);
  block_sum_kernel<<<nb, 256, 0, stream>>>(deg, blockSums, n);
  scan_blocks_kernel<<<1, 1024, 0, stream>>>(blockSums, blockOffs, rowptr, nb, n);
  scan_apply_kernel<<<nb, 256, 0, stream>>>(deg, blockOffs, rowptr, cursor, n);
  scatter_kernel<<<eb, 256, 0, stream>>>(src, dst, cursor, csr_src, E_);

  dim3 gg((n + 63) / 64, 2);

  // layer 0
  gemm128x64<<<gg, 256, 0, stream>>>(x, W0, feat0, feat0b, n);
  node_attn4<<<(n * 4 + 255) / 256, 256, 0, stream>>>(feat0, al0, ar0, el0, er0, n * 4);
  aggregate4<<<(n + 3) / 4, 256, 0, stream>>>(rowptr, csr_src, feat0b, el0, er0, b0, h0, n);

  // layer 1
  gemm128x64<<<gg, 256, 0, stream>>>(h0, W1, feat1, feat1b, n);
  node_attn1<<<(n + 255) / 256, 256, 0, stream>>>(feat1, al1, ar1, el1, er1, n);
  aggregate1<<<(n + 3) / 4, 256, 0, stream>>>(rowptr, csr_src, feat1b, el1, er1, b1, out, n);
}

// Round 5
// 284.297 us; speedup vs baseline: 2.4605x; 1.2817x over previous
//
#include <hip/hip_runtime.h>

#define NEG_SLOPE 0.2f

__device__ inline ushort bf16rne(float f) {
  uint u = __float_as_uint(f);
  u += 0x7fff + ((u >> 16) & 1);
  return (ushort)(u >> 16);
}

// ---------------- GEMM: C[n,128] = A[n,128] @ W[128,128] (fp32 + bf16 copy) --------
__global__ __launch_bounds__(256) void gemm128x64(const float* __restrict__ A,
                                                  const float* __restrict__ W,
                                                  float* __restrict__ C,
                                                  ushort* __restrict__ Cb, int n) {
  __shared__ float sA[64 * 128];
  __shared__ float sW[128 * 64];
  const int t = threadIdx.x;
  const int row0 = blockIdx.x * 64;
  const int col0 = blockIdx.y * 64;
  for (int i = t; i < 2048; i += 256) {
    int r = i >> 5, c4 = i & 31;
    int gr = row0 + r;
    float4 v = make_float4(0.f, 0.f, 0.f, 0.f);
    if (gr < n) v = ((const float4*)(A + (size_t)gr * 128))[c4];
    ((float4*)sA)[i] = v;
  }
  for (int i = t; i < 2048; i += 256) {
    int k = i >> 4, c4 = i & 15;
    ((float4*)sW)[i] = ((const float4*)(W + (size_t)k * 128 + col0))[c4];
  }
  __syncthreads();
  const int tx = t & 15, ty = t >> 4;
  const int c0 = tx * 4, r0 = ty * 4;
  float acc[4][4] = {};
  for (int k = 0; k < 128; k += 4) {
    float4 w0 = *(const float4*)(sW + (k + 0) * 64 + c0);
    float4 w1 = *(const float4*)(sW + (k + 1) * 64 + c0);
    float4 w2 = *(const float4*)(sW + (k + 2) * 64 + c0);
    float4 w3 = *(const float4*)(sW + (k + 3) * 64 + c0);
#pragma unroll
    for (int r = 0; r < 4; ++r) {
      float4 a = *(const float4*)(sA + (r0 + r) * 128 + k);
      acc[r][0] += a.x * w0.x + a.y * w1.x + a.z * w2.x + a.w * w3.x;
      acc[r][1] += a.x * w0.y + a.y * w1.y + a.z * w2.y + a.w * w3.y;
      acc[r][2] += a.x * w0.z + a.y * w1.z + a.z * w2.z + a.w * w3.z;
      acc[r][3] += a.x * w0.w + a.y * w1.w + a.z * w2.w + a.w * w3.w;
    }
  }
#pragma unroll
  for (int r = 0; r < 4; ++r) {
    int gr = row0 + r0 + r;
    if (gr < n) {
      float4 v = make_float4(acc[r][0], acc[r][1], acc[r][2], acc[r][3]);
      *(float4*)(C + (size_t)gr * 128 + col0 + c0) = v;
      ushort4 b;
      b.x = bf16rne(v.x); b.y = bf16rne(v.y);
      b.z = bf16rne(v.z); b.w = bf16rne(v.w);
      *(ushort4*)(Cb + (size_t)gr * 128 + col0 + c0) = b;
    }
  }
}

// ---------------- per-node attention logits (from fp32 feat) ----------------
__global__ __launch_bounds__(256) void node_attn4(const float* __restrict__ feat,
    const float* __restrict__ attn_l, const float* __restrict__ attn_r,
    float* __restrict__ el, float* __restrict__ er, int n4) {
  int i = blockIdx.x * 256 + threadIdx.x;
  if (i >= n4) return;
  const int h = i & 3;
  const float* f = feat + (size_t)i * 32;
  const float* al = attn_l + h * 32;
  const float* ar = attn_r + h * 32;
  float sl = 0.f, sr = 0.f;
#pragma unroll
  for (int k = 0; k < 32; k += 4) {
    float4 v = *(const float4*)(f + k);
    float4 a = *(const float4*)(al + k);
    float4 b = *(const float4*)(ar + k);
    sl += v.x * a.x + v.y * a.y + v.z * a.z + v.w * a.w;
    sr += v.x * b.x + v.y * b.y + v.z * b.z + v.w * b.w;
  }
  el[i] = sl;
  er[i] = sr;
}

__global__ __launch_bounds__(256) void node_attn1(const float* __restrict__ feat,
    const float* __restrict__ attn_l, const float* __restrict__ attn_r,
    float* __restrict__ el, float* __restrict__ er, int n) {
  int i = blockIdx.x * 256 + threadIdx.x;
  if (i >= n) return;
  const float* f = feat + (size_t)i * 128;
  float sl = 0.f, sr = 0.f;
#pragma unroll 8
  for (int k = 0; k < 128; k += 4) {
    float4 v = *(const float4*)(f + k);
    float4 a = *(const float4*)(attn_l + k);
    float4 b = *(const float4*)(attn_r + k);
    sl += v.x * a.x + v.y * a.y + v.z * a.z + v.w * a.w;
    sr += v.x * b.x + v.y * b.y + v.z * b.z + v.w * b.w;
  }
  el[i] = sl;
  er[i] = sr;
}

// ---------------- CSR build ----------------
__global__ void hist_kernel(const int* __restrict__ dst, int* __restrict__ deg, int E_) {
  int i = blockIdx.x * 256 + threadIdx.x;
  if (i < E_) atomicAdd(&deg[dst[i]], 1);
}

__global__ __launch_bounds__(256) void block_sum_kernel(const int* __restrict__ deg,
    int* __restrict__ blockSums, int n) {
  __shared__ int red[256];
  const int t = threadIdx.x;
  int i = blockIdx.x * 256 + t;
  red[t] = (i < n) ? deg[i] : 0;
  __syncthreads();
  for (int off = 128; off > 0; off >>= 1) {
    if (t < off) red[t] += red[t + off];
    __syncthreads();
  }
  if (t == 0) blockSums[blockIdx.x] = red[0];
}

__global__ __launch_bounds__(1024) void scan_blocks_kernel(const int* __restrict__ blockSums,
    int* __restrict__ blockOffs, int* __restrict__ rowptr, int nb, int n) {
  __shared__ int s[1024];
  const int t = threadIdx.x;
  int v = (t < nb) ? blockSums[t] : 0;
  s[t] = v;
  __syncthreads();
  for (int off = 1; off < 1024; off <<= 1) {
    int u = (t >= off) ? s[t - off] : 0;
    __syncthreads();
    s[t] += u;
    __syncthreads();
  }
  if (t < nb) blockOffs[t] = s[t] - v;
  if (t == nb - 1) rowptr[n] = s[t];
}

__global__ __launch_bounds__(256) void scan_apply_kernel(const int* __restrict__ deg,
    const int* __restrict__ blockOffs, int* __restrict__ rowptr,
    int* __restrict__ cursor, int n) {
  __shared__ int s[256];
  const int t = threadIdx.x;
  int i = blockIdx.x * 256 + t;
  int v = (i < n) ? deg[i] : 0;
  s[t] = v;
  __syncthreads();
  for (int off = 1; off < 256; off <<= 1) {
    int u = (t >= off) ? s[t - off] : 0;
    __syncthreads();
    s[t] += u;
    __syncthreads();
  }
  if (i < n) {
    int excl = s[t] - v + blockOffs[blockIdx.x];
    rowptr[i] = excl;
    cursor[i] = excl;
  }
}

__global__ void scatter_kernel(const int* __restrict__ src, const int* __restrict__ dst,
    int* __restrict__ cursor, int* __restrict__ csr_src, int E_) {
  int i = blockIdx.x * 256 + threadIdx.x;
  if (i >= E_) return;
  int p = atomicAdd(&cursor[dst[i]], 1);
  csr_src[p] = src[i];
}

// ---------------- fused edge-softmax + aggregation (bf16 gather, 4x MLP unroll) -----
// wave per dst node; lane owns features 2l,2l+1; 4 edges in flight per iteration
// (batch the independent gathers before any consuming arithmetic).
__global__ __launch_bounds__(256) void aggregate4(const int* __restrict__ rowptr,
    const int* __restrict__ csr_src, const ushort* __restrict__ featb,
    const float* __restrict__ el, const float* __restrict__ er,
    const float* __restrict__ bias, float* __restrict__ out, int n) {
  int node = blockIdx.x * 4 + (threadIdx.x >> 6);
  if (node >= n) return;
  const int lane = threadIdx.x & 63;
  const int f0 = lane * 2;
  const int h = lane >> 4;
  const float erh = er[(size_t)node * 4 + h];
  float a0 = 0.f, a1 = 0.f, d = 0.f;
  const int beg = rowptr[node], end = rowptr[node + 1];
  int idx = beg;
  for (; idx + 3 < end; idx += 4) {
    int s0 = csr_src[idx + 0];
    int s1 = csr_src[idx + 1];
    int s2 = csr_src[idx + 2];
    int s3 = csr_src[idx + 3];
    float l0 = el[(size_t)s0 * 4 + h];
    float l1 = el[(size_t)s1 * 4 + h];
    float l2 = el[(size_t)s2 * 4 + h];
    float l3 = el[(size_t)s3 * 4 + h];
    uint v0 = *(const uint*)(featb + (size_t)s0 * 128 + f0);
    uint v1 = *(const uint*)(featb + (size_t)s1 * 128 + f0);
    uint v2 = *(const uint*)(featb + (size_t)s2 * 128 + f0);
    uint v3 = *(const uint*)(featb + (size_t)s3 * 128 + f0);
    float e0 = l0 + erh; e0 = e0 > 0.f ? e0 : NEG_SLOPE * e0; float w0 = __expf(e0);
    float e1 = l1 + erh; e1 = e1 > 0.f ? e1 : NEG_SLOPE * e1; float w1 = __expf(e1);
    float e2 = l2 + erh; e2 = e2 > 0.f ? e2 : NEG_SLOPE * e2; float w2 = __expf(e2);
    float e3 = l3 + erh; e3 = e3 > 0.f ? e3 : NEG_SLOPE * e3; float w3 = __expf(e3);
    a0 += __uint_as_float(v0 << 16) * w0; a1 += __uint_as_float(v0 & 0xffff0000u) * w0;
    a0 += __uint_as_float(v1 << 16) * w1; a1 += __uint_as_float(v1 & 0xffff0000u) * w1;
    a0 += __uint_as_float(v2 << 16) * w2; a1 += __uint_as_float(v2 & 0xffff0000u) * w2;
    a0 += __uint_as_float(v3 << 16) * w3; a1 += __uint_as_float(v3 & 0xffff0000u) * w3;
    d += w0 + w1 + w2 + w3;
  }
  for (; idx < end; ++idx) {
    int s = csr_src[idx];
    float e = el[(size_t)s * 4 + h] + erh;
    e = e > 0.f ? e : NEG_SLOPE * e;
    float w = __expf(e);
    uint v = *(const uint*)(featb + (size_t)s * 128 + f0);
    a0 += __uint_as_float(v << 16) * w;
    a1 += __uint_as_float(v & 0xffff0000u) * w;
    d += w;
  }
  float inv = d > 0.f ? 1.f / d : 0.f;
  float v0 = a0 * inv + bias[f0];
  v0 = v0 > 0.f ? v0 : __expf(v0) - 1.f;   // ELU
  float v1 = a1 * inv + bias[f0 + 1];
  v1 = v1 > 0.f ? v1 : __expf(v1) - 1.f;
  *(float2*)(out + (size_t)node * 128 + f0) = make_float2(v0, v1);
}

__global__ __launch_bounds__(256) void aggregate1(const int* __restrict__ rowptr,
    const int* __restrict__ csr_src, const ushort* __restrict__ featb,
    const float* __restrict__ el, const float* __restrict__ er,
    const float* __restrict__ bias, float* __restrict__ out, int n) {
  int node = blockIdx.x * 4 + (threadIdx.x >> 6);
  if (node >= n) return;
  const int lane = threadIdx.x & 63;
  const int f0 = lane * 2;
  const float erv = er[node];
  float a0 = 0.f, a1 = 0.f, d = 0.f;
  const int beg = rowptr[node], end = rowptr[node + 1];
  int idx = beg;
  for (; idx + 3 < end; idx += 4) {
    int s0 = csr_src[idx + 0];
    int s1 = csr_src[idx + 1];
    int s2 = csr_src[idx + 2];
    int s3 = csr_src[idx + 3];
    float l0 = el[s0];
    float l1 = el[s1];
    float l2 = el[s2];
    float l3 = el[s3];
    uint v0 = *(const uint*)(featb + (size_t)s0 * 128 + f0);
    uint v1 = *(const uint*)(featb + (size_t)s1 * 128 + f0);
    uint v2 = *(const uint*)(featb + (size_t)s2 * 128 + f0);
    uint v3 = *(const uint*)(featb + (size_t)s3 * 128 + f0);
    float e0 = l0 + erv; e0 = e0 > 0.f ? e0 : NEG_SLOPE * e0; float w0 = __expf(e0);
    float e1 = l1 + erv; e1 = e1 > 0.f ? e1 : NEG_SLOPE * e1; float w1 = __expf(e1);
    float e2 = l2 + erv; e2 = e2 > 0.f ? e2 : NEG_SLOPE * e2; float w2 = __expf(e2);
    float e3 = l3 + erv; e3 = e3 > 0.f ? e3 : NEG_SLOPE * e3; float w3 = __expf(e3);
    a0 += __uint_as_float(v0 << 16) * w0; a1 += __uint_as_float(v0 & 0xffff0000u) * w0;
    a0 += __uint_as_float(v1 << 16) * w1; a1 += __uint_as_float(v1 & 0xffff0000u) * w1;
    a0 += __uint_as_float(v2 << 16) * w2; a1 += __uint_as_float(v2 & 0xffff0000u) * w2;
    a0 += __uint_as_float(v3 << 16) * w3; a1 += __uint_as_float(v3 & 0xffff0000u) * w3;
    d += w0 + w1 + w2 + w3;
  }
  for (; idx < end; ++idx) {
    int s = csr_src[idx];
    float e = el[s] + erv;
    e = e > 0.f ? e : NEG_SLOPE * e;
    float w = __expf(e);
    uint v = *(const uint*)(featb + (size_t)s * 128 + f0);
    a0 += __uint_as_float(v << 16) * w;
    a1 += __uint_as_float(v & 0xffff0000u) * w;
    d += w;
  }
  float inv = d > 0.f ? 1.f / d : 0.f;
  float v0 = a0 * inv + bias[f0];
  v0 = v0 > 0.f ? v0 : __expf(v0) - 1.f;
  float v1 = a1 * inv + bias[f0 + 1];
  v1 = v1 > 0.f ? v1 : __expf(v1) - 1.f;
  *(float2*)(out + (size_t)node * 128 + f0) = make_float2(v0, v1);
}

// ---------------- launch ----------------
extern "C" void kernel_launch(void* const* d_in, const int* in_sizes, int n_in,
                              void* d_out, int out_size, void* d_ws, size_t ws_size,
                              hipStream_t stream) {
  const float* x   = (const float*)d_in[0];
  const int*   src = (const int*)d_in[1];
  const int*   dst = (const int*)d_in[2];
  const float* W0  = (const float*)d_in[3];
  const float* al0 = (const float*)d_in[4];
  const float* ar0 = (const float*)d_in[5];
  const float* b0  = (const float*)d_in[6];
  const float* W1  = (const float*)d_in[7];
  const float* al1 = (const float*)d_in[8];
  const float* ar1 = (const float*)d_in[9];
  const float* b1  = (const float*)d_in[10];
  float* out = (float*)d_out;
  const int n  = in_sizes[0] / 128;
  const int E_ = in_sizes[1];

  char* p = (char*)d_ws;
  auto alloc = [&](size_t bytes) {
    char* r = p;
    p += (bytes + 255) & ~(size_t)255;
    return r;
  };
  float*  feat0  = (float*)alloc((size_t)n * 128 * 4);
  ushort* feat0b = (ushort*)alloc((size_t)n * 128 * 2);
  float*  h0     = (float*)alloc((size_t)n * 128 * 4);
  float*  feat1  = (float*)alloc((size_t)n * 128 * 4);
  ushort* feat1b = (ushort*)alloc((size_t)n * 128 * 2);
  float* el0   = (float*)alloc((size_t)n * 4 * 4);
  float* er0   = (float*)alloc((size_t)n * 4 * 4);
  float* el1   = (float*)alloc((size_t)n * 4);
  float* er1   = (float*)alloc((size_t)n * 4);
  int* deg     = (int*)alloc((size_t)n * 4);
  int* rowptr  = (int*)alloc((size_t)(n + 1) * 4);
  int* cursor  = (int*)alloc((size_t)n * 4);
  int* csr_src = (int*)alloc((size_t)E_ * 4);
  const int nb = (n + 255) / 256;
  int* blockSums = (int*)alloc((size_t)nb * 4);
  int* blockOffs = (int*)alloc((size_t)nb * 4);

  hipMemsetAsync(deg, 0, (size_t)n * 4, stream);

  const int eb = (E_ + 255) / 256;

  // CSR build (graph shared by both layers)
  hist_kernel<<<eb, 256, 0, stream>>>(dst, deg, E_);
  block_sum_kernel<<<nb, 256, 0, stream>>>(deg, blockSums, n);
  scan_blocks_kernel<<<1, 1024, 0, stream>>>(blockSums, blockOffs, rowptr, nb, n);
  scan_apply_kernel<<<nb, 256, 0, stream>>>(deg, blockOffs, rowptr, cursor, n);
  scatter_kernel<<<eb, 256, 0, stream>>>(src, dst, cursor, csr_src, E_);

  dim3 gg((n + 63) / 64, 2);

  // layer 0
  gemm128x64<<<gg, 256, 0, stream>>>(x, W0, feat0, feat0b, n);
  node_attn4<<<(n * 4 + 255) / 256, 256, 0, stream>>>(feat0, al0, ar0, el0, er0, n * 4);
  aggregate4<<<(n + 3) / 4, 256, 0, stream>>>(rowptr, csr_src, feat0b, el0, er0, b0, h0, n);

  // layer 1
  gemm128x64<<<gg, 256, 0, stream>>>(h0, W1, feat1, feat1b, n);
  node_attn1<<<(n + 255) / 256, 256, 0, stream>>>(feat1, al1, ar1, el1, er1, n);
  aggregate1<<<(n + 3) / 4, 256, 0, stream>>>(rowptr, csr_src, feat1b, el1, er1, b1, out, n);
}

// Round 6
// 214.485 us; speedup vs baseline: 3.2614x; 1.3255x over previous
//
#include <hip/hip_runtime.h>

#define NEG_SLOPE 0.2f
#define NBMAX 256   // max coarse buckets (n <= 65536)

__device__ inline ushort bf16rne(float f) {
  uint u = __float_as_uint(f);
  u += 0x7fff + ((u >> 16) & 1);
  return (ushort)(u >> 16);
}

// ---------------- GEMM: C[n,128] = A[n,128] @ W[128,128] (fp32 + bf16 copy) --------
__global__ __launch_bounds__(256) void gemm128x64(const float* __restrict__ A,
                                                  const float* __restrict__ W,
                                                  float* __restrict__ C,
                                                  ushort* __restrict__ Cb, int n) {
  __shared__ float sA[64 * 128];
  __shared__ float sW[128 * 64];
  const int t = threadIdx.x;
  const int row0 = blockIdx.x * 64;
  const int col0 = blockIdx.y * 64;
  for (int i = t; i < 2048; i += 256) {
    int r = i >> 5, c4 = i & 31;
    int gr = row0 + r;
    float4 v = make_float4(0.f, 0.f, 0.f, 0.f);
    if (gr < n) v = ((const float4*)(A + (size_t)gr * 128))[c4];
    ((float4*)sA)[i] = v;
  }
  for (int i = t; i < 2048; i += 256) {
    int k = i >> 4, c4 = i & 15;
    ((float4*)sW)[i] = ((const float4*)(W + (size_t)k * 128 + col0))[c4];
  }
  __syncthreads();
  const int tx = t & 15, ty = t >> 4;
  const int c0 = tx * 4, r0 = ty * 4;
  float acc[4][4] = {};
  for (int k = 0; k < 128; k += 4) {
    float4 w0 = *(const float4*)(sW + (k + 0) * 64 + c0);
    float4 w1 = *(const float4*)(sW + (k + 1) * 64 + c0);
    float4 w2 = *(const float4*)(sW + (k + 2) * 64 + c0);
    float4 w3 = *(const float4*)(sW + (k + 3) * 64 + c0);
#pragma unroll
    for (int r = 0; r < 4; ++r) {
      float4 a = *(const float4*)(sA + (r0 + r) * 128 + k);
      acc[r][0] += a.x * w0.x + a.y * w1.x + a.z * w2.x + a.w * w3.x;
      acc[r][1] += a.x * w0.y + a.y * w1.y + a.z * w2.y + a.w * w3.y;
      acc[r][2] += a.x * w0.z + a.y * w1.z + a.z * w2.z + a.w * w3.z;
      acc[r][3] += a.x * w0.w + a.y * w1.w + a.z * w2.w + a.w * w3.w;
    }
  }
#pragma unroll
  for (int r = 0; r < 4; ++r) {
    int gr = row0 + r0 + r;
    if (gr < n) {
      float4 v = make_float4(acc[r][0], acc[r][1], acc[r][2], acc[r][3]);
      *(float4*)(C + (size_t)gr * 128 + col0 + c0) = v;
      ushort4 b;
      b.x = bf16rne(v.x); b.y = bf16rne(v.y);
      b.z = bf16rne(v.z); b.w = bf16rne(v.w);
      *(ushort4*)(Cb + (size_t)gr * 128 + col0 + c0) = b;
    }
  }
}

// ---------------- per-node attention logits (from fp32 feat) ----------------
__global__ __launch_bounds__(256) void node_attn4(const float* __restrict__ feat,
    const float* __restrict__ attn_l, const float* __restrict__ attn_r,
    float* __restrict__ el, float* __restrict__ er, int n4) {
  int i = blockIdx.x * 256 + threadIdx.x;
  if (i >= n4) return;
  const int h = i & 3;
  const float* f = feat + (size_t)i * 32;
  const float* al = attn_l + h * 32;
  const float* ar = attn_r + h * 32;
  float sl = 0.f, sr = 0.f;
#pragma unroll
  for (int k = 0; k < 32; k += 4) {
    float4 v = *(const float4*)(f + k);
    float4 a = *(const float4*)(al + k);
    float4 b = *(const float4*)(ar + k);
    sl += v.x * a.x + v.y * a.y + v.z * a.z + v.w * a.w;
    sr += v.x * b.x + v.y * b.y + v.z * b.z + v.w * b.w;
  }
  el[i] = sl;
  er[i] = sr;
}

__global__ __launch_bounds__(256) void node_attn1(const float* __restrict__ feat,
    const float* __restrict__ attn_l, const float* __restrict__ attn_r,
    float* __restrict__ el, float* __restrict__ er, int n) {
  int i = blockIdx.x * 256 + threadIdx.x;
  if (i >= n) return;
  const float* f = feat + (size_t)i * 128;
  float sl = 0.f, sr = 0.f;
#pragma unroll 8
  for (int k = 0; k < 128; k += 4) {
    float4 v = *(const float4*)(f + k);
    float4 a = *(const float4*)(attn_l + k);
    float4 b = *(const float4*)(attn_r + k);
    sl += v.x * a.x + v.y * a.y + v.z * a.z + v.w * a.w;
    sr += v.x * b.x + v.y * b.y + v.z * b.z + v.w * b.w;
  }
  el[i] = sl;
  er[i] = sr;
}

// ---------------- CSR build via two-level bucket sort ----------------
// Coarse bucket = dst >> 8 (196 buckets). Packed record: src(16) | dstLow(8)<<16.
__global__ __launch_bounds__(1024) void bucket_count(const int* __restrict__ dst,
    int* __restrict__ bucketCount, int E_) {
  __shared__ int h[NBMAX];
  const int t = threadIdx.x;
  if (t < NBMAX) h[t] = 0;
  __syncthreads();
  const int base = blockIdx.x * 4096;
#pragma unroll
  for (int k = 0; k < 4; ++k) {
    int i = base + k * 1024 + t;
    if (i < E_) atomicAdd(&h[dst[i] >> 8], 1);
  }
  __syncthreads();
  if (t < NBMAX && h[t]) atomicAdd(&bucketCount[t], h[t]);
}

__global__ __launch_bounds__(256) void bucket_scan(const int* __restrict__ bucketCount,
    int* __restrict__ bucketOff, int* __restrict__ bucketCursor,
    int* __restrict__ rowptr, int nb, int n, int E_) {
  __shared__ int s[256];
  const int t = threadIdx.x;
  int v = (t < nb) ? bucketCount[t] : 0;
  s[t] = v;
  __syncthreads();
  for (int off = 1; off < 256; off <<= 1) {
    int u = (t >= off) ? s[t - off] : 0;
    __syncthreads();
    s[t] += u;
    __syncthreads();
  }
  int excl = s[t] - v;
  if (t < nb) { bucketOff[t] = excl; bucketCursor[t] = excl; }
  if (t == nb - 1) { bucketOff[nb] = s[t]; rowptr[n] = E_; }
}

__global__ __launch_bounds__(1024) void bucket_scatter(const int* __restrict__ src,
    const int* __restrict__ dst, int* __restrict__ bucketCursor,
    uint* __restrict__ bucketData, int E_) {
  __shared__ int h[NBMAX];
  __shared__ int bse[NBMAX];
  const int t = threadIdx.x;
  if (t < NBMAX) h[t] = 0;
  __syncthreads();
  const int base = blockIdx.x * 4096;
  int sv[4], dv[4], bk[4];
  bool ok[4];
#pragma unroll
  for (int k = 0; k < 4; ++k) {
    int i = base + k * 1024 + t;
    ok[k] = i < E_;
    if (ok[k]) {
      sv[k] = src[i];
      dv[k] = dst[i];
      bk[k] = dv[k] >> 8;
      atomicAdd(&h[bk[k]], 1);
    }
  }
  __syncthreads();
  if (t < NBMAX) {
    int c = h[t];
    bse[t] = c ? atomicAdd(&bucketCursor[t], c) : 0;
    h[t] = 0;
  }
  __syncthreads();
#pragma unroll
  for (int k = 0; k < 4; ++k) {
    if (ok[k]) {
      int r = atomicAdd(&h[bk[k]], 1);
      bucketData[bse[bk[k]] + r] = (uint)sv[k] | ((uint)(dv[k] & 255) << 16);
    }
  }
}

// one block per coarse bucket: build exact per-node CSR segment in LDS
__global__ __launch_bounds__(1024) void fine_csr(const uint* __restrict__ bucketData,
    const int* __restrict__ bucketOff, int* __restrict__ rowptr,
    int* __restrict__ csr_src, int n) {
  __shared__ int fh[256];
  __shared__ int fx[256];
  const int b = blockIdx.x;
  const int t = threadIdx.x;
  const int beg = bucketOff[b];
  const int cnt = bucketOff[b + 1] - beg;
  if (t < 256) fh[t] = 0;
  __syncthreads();
  for (int i = t; i < cnt; i += 1024) atomicAdd(&fh[bucketData[beg + i] >> 16], 1);
  __syncthreads();
  if (t < 256) fx[t] = fh[t];
  __syncthreads();
  for (int off = 1; off < 256; off <<= 1) {
    int u = 0;
    if (t < 256 && t >= off) u = fx[t - off];
    __syncthreads();
    if (t < 256) fx[t] += u;
    __syncthreads();
  }
  if (t < 256) {
    int excl = fx[t] - fh[t];
    int node = b * 256 + t;
    if (node < n) rowptr[node] = beg + excl;
    fh[t] = excl;        // reuse as intra-bucket cursor
  }
  __syncthreads();
  for (int i = t; i < cnt; i += 1024) {
    uint rec = bucketData[beg + i];
    int r = atomicAdd(&fh[rec >> 16], 1);
    csr_src[beg + r] = (int)(rec & 0xffffu);
  }
}

// ---------------- fused edge-softmax + aggregation (bf16 gather, 4x MLP unroll) -----
__global__ __launch_bounds__(256) void aggregate4(const int* __restrict__ rowptr,
    const int* __restrict__ csr_src, const ushort* __restrict__ featb,
    const float* __restrict__ el, const float* __restrict__ er,
    const float* __restrict__ bias, float* __restrict__ out, int n) {
  int node = blockIdx.x * 4 + (threadIdx.x >> 6);
  if (node >= n) return;
  const int lane = threadIdx.x & 63;
  const int f0 = lane * 2;
  const int h = lane >> 4;
  const float erh = er[(size_t)node * 4 + h];
  float a0 = 0.f, a1 = 0.f, d = 0.f;
  const int beg = rowptr[node], end = rowptr[node + 1];
  int idx = beg;
  for (; idx + 3 < end; idx += 4) {
    int s0 = csr_src[idx + 0];
    int s1 = csr_src[idx + 1];
    int s2 = csr_src[idx + 2];
    int s3 = csr_src[idx + 3];
    float l0 = el[(size_t)s0 * 4 + h];
    float l1 = el[(size_t)s1 * 4 + h];
    float l2 = el[(size_t)s2 * 4 + h];
    float l3 = el[(size_t)s3 * 4 + h];
    uint v0 = *(const uint*)(featb + (size_t)s0 * 128 + f0);
    uint v1 = *(const uint*)(featb + (size_t)s1 * 128 + f0);
    uint v2 = *(const uint*)(featb + (size_t)s2 * 128 + f0);
    uint v3 = *(const uint*)(featb + (size_t)s3 * 128 + f0);
    float e0 = l0 + erh; e0 = e0 > 0.f ? e0 : NEG_SLOPE * e0; float w0 = __expf(e0);
    float e1 = l1 + erh; e1 = e1 > 0.f ? e1 : NEG_SLOPE * e1; float w1 = __expf(e1);
    float e2 = l2 + erh; e2 = e2 > 0.f ? e2 : NEG_SLOPE * e2; float w2 = __expf(e2);
    float e3 = l3 + erh; e3 = e3 > 0.f ? e3 : NEG_SLOPE * e3; float w3 = __expf(e3);
    a0 += __uint_as_float(v0 << 16) * w0; a1 += __uint_as_float(v0 & 0xffff0000u) * w0;
    a0 += __uint_as_float(v1 << 16) * w1; a1 += __uint_as_float(v1 & 0xffff0000u) * w1;
    a0 += __uint_as_float(v2 << 16) * w2; a1 += __uint_as_float(v2 & 0xffff0000u) * w2;
    a0 += __uint_as_float(v3 << 16) * w3; a1 += __uint_as_float(v3 & 0xffff0000u) * w3;
    d += w0 + w1 + w2 + w3;
  }
  for (; idx < end; ++idx) {
    int s = csr_src[idx];
    float e = el[(size_t)s * 4 + h] + erh;
    e = e > 0.f ? e : NEG_SLOPE * e;
    float w = __expf(e);
    uint v = *(const uint*)(featb + (size_t)s * 128 + f0);
    a0 += __uint_as_float(v << 16) * w;
    a1 += __uint_as_float(v & 0xffff0000u) * w;
    d += w;
  }
  float inv = d > 0.f ? 1.f / d : 0.f;
  float v0 = a0 * inv + bias[f0];
  v0 = v0 > 0.f ? v0 : __expf(v0) - 1.f;   // ELU
  float v1 = a1 * inv + bias[f0 + 1];
  v1 = v1 > 0.f ? v1 : __expf(v1) - 1.f;
  *(float2*)(out + (size_t)node * 128 + f0) = make_float2(v0, v1);
}

__global__ __launch_bounds__(256) void aggregate1(const int* __restrict__ rowptr,
    const int* __restrict__ csr_src, const ushort* __restrict__ featb,
    const float* __restrict__ el, const float* __restrict__ er,
    const float* __restrict__ bias, float* __restrict__ out, int n) {
  int node = blockIdx.x * 4 + (threadIdx.x >> 6);
  if (node >= n) return;
  const int lane = threadIdx.x & 63;
  const int f0 = lane * 2;
  const float erv = er[node];
  float a0 = 0.f, a1 = 0.f, d = 0.f;
  const int beg = rowptr[node], end = rowptr[node + 1];
  int idx = beg;
  for (; idx + 3 < end; idx += 4) {
    int s0 = csr_src[idx + 0];
    int s1 = csr_src[idx + 1];
    int s2 = csr_src[idx + 2];
    int s3 = csr_src[idx + 3];
    float l0 = el[s0];
    float l1 = el[s1];
    float l2 = el[s2];
    float l3 = el[s3];
    uint v0 = *(const uint*)(featb + (size_t)s0 * 128 + f0);
    uint v1 = *(const uint*)(featb + (size_t)s1 * 128 + f0);
    uint v2 = *(const uint*)(featb + (size_t)s2 * 128 + f0);
    uint v3 = *(const uint*)(featb + (size_t)s3 * 128 + f0);
    float e0 = l0 + erv; e0 = e0 > 0.f ? e0 : NEG_SLOPE * e0; float w0 = __expf(e0);
    float e1 = l1 + erv; e1 = e1 > 0.f ? e1 : NEG_SLOPE * e1; float w1 = __expf(e1);
    float e2 = l2 + erv; e2 = e2 > 0.f ? e2 : NEG_SLOPE * e2; float w2 = __expf(e2);
    float e3 = l3 + erv; e3 = e3 > 0.f ? e3 : NEG_SLOPE * e3; float w3 = __expf(e3);
    a0 += __uint_as_float(v0 << 16) * w0; a1 += __uint_as_float(v0 & 0xffff0000u) * w0;
    a0 += __uint_as_float(v1 << 16) * w1; a1 += __uint_as_float(v1 & 0xffff0000u) * w1;
    a0 += __uint_as_float(v2 << 16) * w2; a1 += __uint_as_float(v2 & 0xffff0000u) * w2;
    a0 += __uint_as_float(v3 << 16) * w3; a1 += __uint_as_float(v3 & 0xffff0000u) * w3;
    d += w0 + w1 + w2 + w3;
  }
  for (; idx < end; ++idx) {
    int s = csr_src[idx];
    float e = el[s] + erv;
    e = e > 0.f ? e : NEG_SLOPE * e;
    float w = __expf(e);
    uint v = *(const uint*)(featb + (size_t)s * 128 + f0);
    a0 += __uint_as_float(v << 16) * w;
    a1 += __uint_as_float(v & 0xffff0000u) * w;
    d += w;
  }
  float inv = d > 0.f ? 1.f / d : 0.f;
  float v0 = a0 * inv + bias[f0];
  v0 = v0 > 0.f ? v0 : __expf(v0) - 1.f;
  float v1 = a1 * inv + bias[f0 + 1];
  v1 = v1 > 0.f ? v1 : __expf(v1) - 1.f;
  *(float2*)(out + (size_t)node * 128 + f0) = make_float2(v0, v1);
}

// ---------------- launch ----------------
extern "C" void kernel_launch(void* const* d_in, const int* in_sizes, int n_in,
                              void* d_out, int out_size, void* d_ws, size_t ws_size,
                              hipStream_t stream) {
  const float* x   = (const float*)d_in[0];
  const int*   src = (const int*)d_in[1];
  const int*   dst = (const int*)d_in[2];
  const float* W0  = (const float*)d_in[3];
  const float* al0 = (const float*)d_in[4];
  const float* ar0 = (const float*)d_in[5];
  const float* b0  = (const float*)d_in[6];
  const float* W1  = (const float*)d_in[7];
  const float* al1 = (const float*)d_in[8];
  const float* ar1 = (const float*)d_in[9];
  const float* b1  = (const float*)d_in[10];
  float* out = (float*)d_out;
  const int n  = in_sizes[0] / 128;
  const int E_ = in_sizes[1];

  char* p = (char*)d_ws;
  auto alloc = [&](size_t bytes) {
    char* r = p;
    p += (bytes + 255) & ~(size_t)255;
    return r;
  };
  float*  feat0  = (float*)alloc((size_t)n * 128 * 4);
  ushort* feat0b = (ushort*)alloc((size_t)n * 128 * 2);
  float*  h0     = (float*)alloc((size_t)n * 128 * 4);
  float*  feat1  = (float*)alloc((size_t)n * 128 * 4);
  ushort* feat1b = (ushort*)alloc((size_t)n * 128 * 2);
  float* el0   = (float*)alloc((size_t)n * 4 * 4);
  float* er0   = (float*)alloc((size_t)n * 4 * 4);
  float* el1   = (float*)alloc((size_t)n * 4);
  float* er1   = (float*)alloc((size_t)n * 4);
  int* rowptr  = (int*)alloc((size_t)(n + 1) * 4);
  int* csr_src = (int*)alloc((size_t)E_ * 4);
  uint* bucketData  = (uint*)alloc((size_t)E_ * 4);
  int* bucketCount  = (int*)alloc(NBMAX * 4);
  int* bucketOff    = (int*)alloc((NBMAX + 1) * 4);
  int* bucketCursor = (int*)alloc(NBMAX * 4);

  const int nbk = (n + 255) >> 8;           // coarse buckets (196)
  const int gb  = (E_ + 4095) / 4096;       // edge blocks for count/scatter

  hipMemsetAsync(bucketCount, 0, NBMAX * 4, stream);

  // CSR build (graph shared by both layers)
  bucket_count<<<gb, 1024, 0, stream>>>(dst, bucketCount, E_);
  bucket_scan<<<1, 256, 0, stream>>>(bucketCount, bucketOff, bucketCursor, rowptr, nbk, n, E_);
  bucket_scatter<<<gb, 1024, 0, stream>>>(src, dst, bucketCursor, bucketData, E_);
  fine_csr<<<nbk, 1024, 0, stream>>>(bucketData, bucketOff, rowptr, csr_src, n);

  dim3 gg((n + 63) / 64, 2);

  // layer 0
  gemm128x64<<<gg, 256, 0, stream>>>(x, W0, feat0, feat0b, n);
  node_attn4<<<(n * 4 + 255) / 256, 256, 0, stream>>>(feat0, al0, ar0, el0, er0, n * 4);
  aggregate4<<<(n + 3) / 4, 256, 0, stream>>>(rowptr, csr_src, feat0b, el0, er0, b0, h0, n);

  // layer 1
  gemm128x64<<<gg, 256, 0, stream>>>(h0, W1, feat1, feat1b, n);
  node_attn1<<<(n + 255) / 256, 256, 0, stream>>>(feat1, al1, ar1, el1, er1, n);
  aggregate1<<<(n + 3) / 4, 256, 0, stream>>>(rowptr, csr_src, feat1b, el1, er1, b1, out, n);
}

// Round 7
// 196.491 us; speedup vs baseline: 3.5601x; 1.0916x over previous
//
#include <hip/hip_runtime.h>

#define NEG_SLOPE 0.2f
#define NBMAX 256   // max coarse buckets (n <= 65536)

typedef __attribute__((ext_vector_type(8))) short bf16x8;
typedef __attribute__((ext_vector_type(16))) float f32x16;

__device__ inline ushort bf16rne(float f) {
  uint u = __float_as_uint(f);
  u += 0x7fff + ((u >> 16) & 1);
  return (ushort)(u >> 16);
}
__device__ inline float bf2f(ushort h) { return __uint_as_float((uint)h << 16); }

// XOR swizzle within a 256B LDS row: spreads 16B slots across banks
#define XS(row, byte) ((byte) ^ (((row) & 15) << 4))

// ---------------- prep: W[k][n] fp32 -> Wt_hi/Wt_lo bf16 [n][k] ----------------
__global__ __launch_bounds__(256) void splitW(const float* __restrict__ W,
    ushort* __restrict__ Wh, ushort* __restrict__ Wl) {
  int i = blockIdx.x * 256 + threadIdx.x;     // 16384 elements
  int k = i >> 7, nn = i & 127;
  float w = W[i];
  ushort h = bf16rne(w);
  float lo = w - bf2f(h);
  Wh[nn * 128 + k] = h;
  Wl[nn * 128 + k] = bf16rne(lo);
}

// ---------------- MFMA GEMM: C[n,128] = A[n,128] @ W[128,128] ----------------
// hi/lo bf16 split (3 mfma per k-step) for fp32-grade accuracy.
// block: 64 rows x 64 cols, 4 waves, wave = one 32x32 output tile, K=128.
__global__ __launch_bounds__(256) void gemm_mfma(const float* __restrict__ A,
    const ushort* __restrict__ Wh, const ushort* __restrict__ Wl,
    float* __restrict__ C, ushort* __restrict__ Cb, int n) {
  __shared__ __align__(16) ushort sAh[64 * 128];
  __shared__ __align__(16) ushort sAl[64 * 128];
  __shared__ __align__(16) ushort sBh[64 * 128];
  __shared__ __align__(16) ushort sBl[64 * 128];
  const int t = threadIdx.x;
  const int row0 = blockIdx.x * 64;
  const int col0 = blockIdx.y * 64;
  // stage A (64x128 fp32 -> hi/lo bf16), swizzled
  for (int i = t; i < 2048; i += 256) {
    int r = i >> 5, c4 = i & 31;
    int gr = row0 + r;
    float4 v = make_float4(0.f, 0.f, 0.f, 0.f);
    if (gr < n) v = ((const float4*)(A + (size_t)gr * 128))[c4];
    ushort4 h, l;
    h.x = bf16rne(v.x); l.x = bf16rne(v.x - bf2f(h.x));
    h.y = bf16rne(v.y); l.y = bf16rne(v.y - bf2f(h.y));
    h.z = bf16rne(v.z); l.z = bf16rne(v.z - bf2f(h.z));
    h.w = bf16rne(v.w); l.w = bf16rne(v.w - bf2f(h.w));
    int byte = XS(r, r * 256 + c4 * 8);
    *(ushort4*)((char*)sAh + byte) = h;
    *(ushort4*)((char*)sAl + byte) = l;
  }
  // stage B = Wt rows col0..col0+63 (bf16, already transposed), swizzled
  for (int i = t; i < 1024; i += 256) {
    int r = i >> 4, q = i & 15;
    int byte = XS(r, r * 256 + q * 16);
    *(uint4*)((char*)sBh + byte) = ((const uint4*)(Wh + (size_t)(col0 + r) * 128))[q];
    *(uint4*)((char*)sBl + byte) = ((const uint4*)(Wl + (size_t)(col0 + r) * 128))[q];
  }
  __syncthreads();
  const int w = t >> 6, lane = t & 63;
  const int rbase = (w >> 1) * 32;   // local row base of this wave's tile
  const int cbase = (w & 1) * 32;    // local col base
  const int lr = lane & 31;
  const int hi = lane >> 5;          // k-half selector
  const int arow = rbase + lr;
  const int brow = cbase + lr;
  f32x16 acc0 = {};
  f32x16 acc1 = {};
#pragma unroll
  for (int ks = 0; ks < 8; ++ks) {
    int kb = (ks * 16 + hi * 8) * 2;
    bf16x8 ah = *(bf16x8*)((char*)sAh + XS(arow, arow * 256 + kb));
    bf16x8 al = *(bf16x8*)((char*)sAl + XS(arow, arow * 256 + kb));
    bf16x8 bh = *(bf16x8*)((char*)sBh + XS(brow, brow * 256 + kb));
    bf16x8 bl = *(bf16x8*)((char*)sBl + XS(brow, brow * 256 + kb));
    if (ks & 1) {
      acc1 = __builtin_amdgcn_mfma_f32_32x32x16_bf16(ah, bh, acc1, 0, 0, 0);
      acc1 = __builtin_amdgcn_mfma_f32_32x32x16_bf16(ah, bl, acc1, 0, 0, 0);
      acc1 = __builtin_amdgcn_mfma_f32_32x32x16_bf16(al, bh, acc1, 0, 0, 0);
    } else {
      acc0 = __builtin_amdgcn_mfma_f32_32x32x16_bf16(ah, bh, acc0, 0, 0, 0);
      acc0 = __builtin_amdgcn_mfma_f32_32x32x16_bf16(ah, bl, acc0, 0, 0, 0);
      acc0 = __builtin_amdgcn_mfma_f32_32x32x16_bf16(al, bh, acc0, 0, 0, 0);
    }
  }
  const int gcol = col0 + cbase + lr;
#pragma unroll
  for (int r = 0; r < 16; ++r) {
    int grow = row0 + rbase + (r & 3) + 8 * (r >> 2) + 4 * hi;
    if (grow < n) {
      float v = acc0[r] + acc1[r];
      C[(size_t)grow * 128 + gcol] = v;
      Cb[(size_t)grow * 128 + gcol] = bf16rne(v);
    }
  }
}

// ---------------- per-node attention logits (from fp32 feat) ----------------
__global__ __launch_bounds__(256) void node_attn4(const float* __restrict__ feat,
    const float* __restrict__ attn_l, const float* __restrict__ attn_r,
    float* __restrict__ el, float* __restrict__ er, int n4) {
  int i = blockIdx.x * 256 + threadIdx.x;
  if (i >= n4) return;
  const int h = i & 3;
  const float* f = feat + (size_t)i * 32;
  const float* al = attn_l + h * 32;
  const float* ar = attn_r + h * 32;
  float sl = 0.f, sr = 0.f;
#pragma unroll
  for (int k = 0; k < 32; k += 4) {
    float4 v = *(const float4*)(f + k);
    float4 a = *(const float4*)(al + k);
    float4 b = *(const float4*)(ar + k);
    sl += v.x * a.x + v.y * a.y + v.z * a.z + v.w * a.w;
    sr += v.x * b.x + v.y * b.y + v.z * b.z + v.w * b.w;
  }
  el[i] = sl;
  er[i] = sr;
}

__global__ __launch_bounds__(256) void node_attn1(const float* __restrict__ feat,
    const float* __restrict__ attn_l, const float* __restrict__ attn_r,
    float* __restrict__ el, float* __restrict__ er, int n) {
  int i = blockIdx.x * 256 + threadIdx.x;
  if (i >= n) return;
  const float* f = feat + (size_t)i * 128;
  float sl = 0.f, sr = 0.f;
#pragma unroll 8
  for (int k = 0; k < 128; k += 4) {
    float4 v = *(const float4*)(f + k);
    float4 a = *(const float4*)(attn_l + k);
    float4 b = *(const float4*)(attn_r + k);
    sl += v.x * a.x + v.y * a.y + v.z * a.z + v.w * a.w;
    sr += v.x * b.x + v.y * b.y + v.z * b.z + v.w * b.w;
  }
  el[i] = sl;
  er[i] = sr;
}

// ---------------- CSR build via two-level bucket sort ----------------
__global__ __launch_bounds__(1024) void bucket_count(const int* __restrict__ dst,
    int* __restrict__ bucketCount, int E_) {
  __shared__ int h[NBMAX];
  const int t = threadIdx.x;
  if (t < NBMAX) h[t] = 0;
  __syncthreads();
  const int base = blockIdx.x * 4096;
#pragma unroll
  for (int k = 0; k < 4; ++k) {
    int i = base + k * 1024 + t;
    if (i < E_) atomicAdd(&h[dst[i] >> 8], 1);
  }
  __syncthreads();
  if (t < NBMAX && h[t]) atomicAdd(&bucketCount[t], h[t]);
}

__global__ __launch_bounds__(256) void bucket_scan(const int* __restrict__ bucketCount,
    int* __restrict__ bucketOff, int* __restrict__ bucketCursor,
    int* __restrict__ rowptr, int nb, int n, int E_) {
  __shared__ int s[256];
  const int t = threadIdx.x;
  int v = (t < nb) ? bucketCount[t] : 0;
  s[t] = v;
  __syncthreads();
  for (int off = 1; off < 256; off <<= 1) {
    int u = (t >= off) ? s[t - off] : 0;
    __syncthreads();
    s[t] += u;
    __syncthreads();
  }
  int excl = s[t] - v;
  if (t < nb) { bucketOff[t] = excl; bucketCursor[t] = excl; }
  if (t == nb - 1) { bucketOff[nb] = s[t]; rowptr[n] = E_; }
}

__global__ __launch_bounds__(1024) void bucket_scatter(const int* __restrict__ src,
    const int* __restrict__ dst, int* __restrict__ bucketCursor,
    uint* __restrict__ bucketData, int E_) {
  __shared__ int h[NBMAX];
  __shared__ int bse[NBMAX];
  const int t = threadIdx.x;
  if (t < NBMAX) h[t] = 0;
  __syncthreads();
  const int base = blockIdx.x * 4096;
  int sv[4], dv[4], bk[4];
  bool ok[4];
#pragma unroll
  for (int k = 0; k < 4; ++k) {
    int i = base + k * 1024 + t;
    ok[k] = i < E_;
    if (ok[k]) {
      sv[k] = src[i];
      dv[k] = dst[i];
      bk[k] = dv[k] >> 8;
      atomicAdd(&h[bk[k]], 1);
    }
  }
  __syncthreads();
  if (t < NBMAX) {
    int c = h[t];
    bse[t] = c ? atomicAdd(&bucketCursor[t], c) : 0;
    h[t] = 0;
  }
  __syncthreads();
#pragma unroll
  for (int k = 0; k < 4; ++k) {
    if (ok[k]) {
      int r = atomicAdd(&h[bk[k]], 1);
      bucketData[bse[bk[k]] + r] = (uint)sv[k] | ((uint)(dv[k] & 255) << 16);
    }
  }
}

__global__ __launch_bounds__(1024) void fine_csr(const uint* __restrict__ bucketData,
    const int* __restrict__ bucketOff, int* __restrict__ rowptr,
    int* __restrict__ csr_src, int n) {
  __shared__ int fh[256];
  __shared__ int fx[256];
  const int b = blockIdx.x;
  const int t = threadIdx.x;
  const int beg = bucketOff[b];
  const int cnt = bucketOff[b + 1] - beg;
  if (t < 256) fh[t] = 0;
  __syncthreads();
  for (int i = t; i < cnt; i += 1024) atomicAdd(&fh[bucketData[beg + i] >> 16], 1);
  __syncthreads();
  if (t < 256) fx[t] = fh[t];
  __syncthreads();
  for (int off = 1; off < 256; off <<= 1) {
    int u = 0;
    if (t < 256 && t >= off) u = fx[t - off];
    __syncthreads();
    if (t < 256) fx[t] += u;
    __syncthreads();
  }
  if (t < 256) {
    int excl = fx[t] - fh[t];
    int node = b * 256 + t;
    if (node < n) rowptr[node] = beg + excl;
    fh[t] = excl;
  }
  __syncthreads();
  for (int i = t; i < cnt; i += 1024) {
    uint rec = bucketData[beg + i];
    int r = atomicAdd(&fh[rec >> 16], 1);
    csr_src[beg + r] = (int)(rec & 0xffffu);
  }
}

// ---------------- fused edge-softmax + aggregation (bf16 gather, 4x MLP unroll) -----
__global__ __launch_bounds__(256) void aggregate4(const int* __restrict__ rowptr,
    const int* __restrict__ csr_src, const ushort* __restrict__ featb,
    const float* __restrict__ el, const float* __restrict__ er,
    const float* __restrict__ bias, float* __restrict__ out, int n) {
  int node = blockIdx.x * 4 + (threadIdx.x >> 6);
  if (node >= n) return;
  const int lane = threadIdx.x & 63;
  const int f0 = lane * 2;
  const int h = lane >> 4;
  const float erh = er[(size_t)node * 4 + h];
  float a0 = 0.f, a1 = 0.f, d = 0.f;
  const int beg = rowptr[node], end = rowptr[node + 1];
  int idx = beg;
  for (; idx + 3 < end; idx += 4) {
    int s0 = csr_src[idx + 0];
    int s1 = csr_src[idx + 1];
    int s2 = csr_src[idx + 2];
    int s3 = csr_src[idx + 3];
    float l0 = el[(size_t)s0 * 4 + h];
    float l1 = el[(size_t)s1 * 4 + h];
    float l2 = el[(size_t)s2 * 4 + h];
    float l3 = el[(size_t)s3 * 4 + h];
    uint v0 = *(const uint*)(featb + (size_t)s0 * 128 + f0);
    uint v1 = *(const uint*)(featb + (size_t)s1 * 128 + f0);
    uint v2 = *(const uint*)(featb + (size_t)s2 * 128 + f0);
    uint v3 = *(const uint*)(featb + (size_t)s3 * 128 + f0);
    float e0 = l0 + erh; e0 = e0 > 0.f ? e0 : NEG_SLOPE * e0; float w0 = __expf(e0);
    float e1 = l1 + erh; e1 = e1 > 0.f ? e1 : NEG_SLOPE * e1; float w1 = __expf(e1);
    float e2 = l2 + erh; e2 = e2 > 0.f ? e2 : NEG_SLOPE * e2; float w2 = __expf(e2);
    float e3 = l3 + erh; e3 = e3 > 0.f ? e3 : NEG_SLOPE * e3; float w3 = __expf(e3);
    a0 += __uint_as_float(v0 << 16) * w0; a1 += __uint_as_float(v0 & 0xffff0000u) * w0;
    a0 += __uint_as_float(v1 << 16) * w1; a1 += __uint_as_float(v1 & 0xffff0000u) * w1;
    a0 += __uint_as_float(v2 << 16) * w2; a1 += __uint_as_float(v2 & 0xffff0000u) * w2;
    a0 += __uint_as_float(v3 << 16) * w3; a1 += __uint_as_float(v3 & 0xffff0000u) * w3;
    d += w0 + w1 + w2 + w3;
  }
  for (; idx < end; ++idx) {
    int s = csr_src[idx];
    float e = el[(size_t)s * 4 + h] + erh;
    e = e > 0.f ? e : NEG_SLOPE * e;
    float w = __expf(e);
    uint v = *(const uint*)(featb + (size_t)s * 128 + f0);
    a0 += __uint_as_float(v << 16) * w;
    a1 += __uint_as_float(v & 0xffff0000u) * w;
    d += w;
  }
  float inv = d > 0.f ? 1.f / d : 0.f;
  float v0 = a0 * inv + bias[f0];
  v0 = v0 > 0.f ? v0 : __expf(v0) - 1.f;   // ELU
  float v1 = a1 * inv + bias[f0 + 1];
  v1 = v1 > 0.f ? v1 : __expf(v1) - 1.f;
  *(float2*)(out + (size_t)node * 128 + f0) = make_float2(v0, v1);
}

__global__ __launch_bounds__(256) void aggregate1(const int* __restrict__ rowptr,
    const int* __restrict__ csr_src, const ushort* __restrict__ featb,
    const float* __restrict__ el, const float* __restrict__ er,
    const float* __restrict__ bias, float* __restrict__ out, int n) {
  int node = blockIdx.x * 4 + (threadIdx.x >> 6);
  if (node >= n) return;
  const int lane = threadIdx.x & 63;
  const int f0 = lane * 2;
  const float erv = er[node];
  float a0 = 0.f, a1 = 0.f, d = 0.f;
  const int beg = rowptr[node], end = rowptr[node + 1];
  int idx = beg;
  for (; idx + 3 < end; idx += 4) {
    int s0 = csr_src[idx + 0];
    int s1 = csr_src[idx + 1];
    int s2 = csr_src[idx + 2];
    int s3 = csr_src[idx + 3];
    float l0 = el[s0];
    float l1 = el[s1];
    float l2 = el[s2];
    float l3 = el[s3];
    uint v0 = *(const uint*)(featb + (size_t)s0 * 128 + f0);
    uint v1 = *(const uint*)(featb + (size_t)s1 * 128 + f0);
    uint v2 = *(const uint*)(featb + (size_t)s2 * 128 + f0);
    uint v3 = *(const uint*)(featb + (size_t)s3 * 128 + f0);
    float e0 = l0 + erv; e0 = e0 > 0.f ? e0 : NEG_SLOPE * e0; float w0 = __expf(e0);
    float e1 = l1 + erv; e1 = e1 > 0.f ? e1 : NEG_SLOPE * e1; float w1 = __expf(e1);
    float e2 = l2 + erv; e2 = e2 > 0.f ? e2 : NEG_SLOPE * e2; float w2 = __expf(e2);
    float e3 = l3 + erv; e3 = e3 > 0.f ? e3 : NEG_SLOPE * e3; float w3 = __expf(e3);
    a0 += __uint_as_float(v0 << 16) * w0; a1 += __uint_as_float(v0 & 0xffff0000u) * w0;
    a0 += __uint_as_float(v1 << 16) * w1; a1 += __uint_as_float(v1 & 0xffff0000u) * w1;
    a0 += __uint_as_float(v2 << 16) * w2; a1 += __uint_as_float(v2 & 0xffff0000u) * w2;
    a0 += __uint_as_float(v3 << 16) * w3; a1 += __uint_as_float(v3 & 0xffff0000u) * w3;
    d += w0 + w1 + w2 + w3;
  }
  for (; idx < end; ++idx) {
    int s = csr_src[idx];
    float e = el[s] + erv;
    e = e > 0.f ? e : NEG_SLOPE * e;
    float w = __expf(e);
    uint v = *(const uint*)(featb + (size_t)s * 128 + f0);
    a0 += __uint_as_float(v << 16) * w;
    a1 += __uint_as_float(v & 0xffff0000u) * w;
    d += w;
  }
  float inv = d > 0.f ? 1.f / d : 0.f;
  float v0 = a0 * inv + bias[f0];
  v0 = v0 > 0.f ? v0 : __expf(v0) - 1.f;
  float v1 = a1 * inv + bias[f0 + 1];
  v1 = v1 > 0.f ? v1 : __expf(v1) - 1.f;
  *(float2*)(out + (size_t)node * 128 + f0) = make_float2(v0, v1);
}

// ---------------- launch ----------------
extern "C" void kernel_launch(void* const* d_in, const int* in_sizes, int n_in,
                              void* d_out, int out_size, void* d_ws, size_t ws_size,
                              hipStream_t stream) {
  const float* x   = (const float*)d_in[0];
  const int*   src = (const int*)d_in[1];
  const int*   dst = (const int*)d_in[2];
  const float* W0  = (const float*)d_in[3];
  const float* al0 = (const float*)d_in[4];
  const float* ar0 = (const float*)d_in[5];
  const float* b0  = (const float*)d_in[6];
  const float* W1  = (const float*)d_in[7];
  const float* al1 = (const float*)d_in[8];
  const float* ar1 = (const float*)d_in[9];
  const float* b1  = (const float*)d_in[10];
  float* out = (float*)d_out;
  const int n  = in_sizes[0] / 128;
  const int E_ = in_sizes[1];

  char* p = (char*)d_ws;
  auto alloc = [&](size_t bytes) {
    char* r = p;
    p += (bytes + 255) & ~(size_t)255;
    return r;
  };
  float*  feat0  = (float*)alloc((size_t)n * 128 * 4);
  ushort* feat0b = (ushort*)alloc((size_t)n * 128 * 2);
  float*  h0     = (float*)alloc((size_t)n * 128 * 4);
  float*  feat1  = (float*)alloc((size_t)n * 128 * 4);
  ushort* feat1b = (ushort*)alloc((size_t)n * 128 * 2);
  float* el0   = (float*)alloc((size_t)n * 4 * 4);
  float* er0   = (float*)alloc((size_t)n * 4 * 4);
  float* el1   = (float*)alloc((size_t)n * 4);
  float* er1   = (float*)alloc((size_t)n * 4);
  int* rowptr  = (int*)alloc((size_t)(n + 1) * 4);
  int* csr_src = (int*)alloc((size_t)E_ * 4);
  uint* bucketData  = (uint*)alloc((size_t)E_ * 4);
  int* bucketCount  = (int*)alloc(NBMAX * 4);
  int* bucketOff    = (int*)alloc((NBMAX + 1) * 4);
  int* bucketCursor = (int*)alloc(NBMAX * 4);
  ushort* W0h = (ushort*)alloc(128 * 128 * 2);
  ushort* W0l = (ushort*)alloc(128 * 128 * 2);
  ushort* W1h = (ushort*)alloc(128 * 128 * 2);
  ushort* W1l = (ushort*)alloc(128 * 128 * 2);

  const int nbk = (n + 255) >> 8;
  const int gb  = (E_ + 4095) / 4096;

  hipMemsetAsync(bucketCount, 0, NBMAX * 4, stream);

  // weight prep (tiny)
  splitW<<<64, 256, 0, stream>>>(W0, W0h, W0l);
  splitW<<<64, 256, 0, stream>>>(W1, W1h, W1l);

  // CSR build (graph shared by both layers)
  bucket_count<<<gb, 1024, 0, stream>>>(dst, bucketCount, E_);
  bucket_scan<<<1, 256, 0, stream>>>(bucketCount, bucketOff, bucketCursor, rowptr, nbk, n, E_);
  bucket_scatter<<<gb, 1024, 0, stream>>>(src, dst, bucketCursor, bucketData, E_);
  fine_csr<<<nbk, 1024, 0, stream>>>(bucketData, bucketOff, rowptr, csr_src, n);

  dim3 gg((n + 63) / 64, 2);

  // layer 0
  gemm_mfma<<<gg, 256, 0, stream>>>(x, W0h, W0l, feat0, feat0b, n);
  node_attn4<<<(n * 4 + 255) / 256, 256, 0, stream>>>(feat0, al0, ar0, el0, er0, n * 4);
  aggregate4<<<(n + 3) / 4, 256, 0, stream>>>(rowptr, csr_src, feat0b, el0, er0, b0, h0, n);

  // layer 1
  gemm_mfma<<<gg, 256, 0, stream>>>(h0, W1h, W1l, feat1, feat1b, n);
  node_attn1<<<(n + 255) / 256, 256, 0, stream>>>(feat1, al1, ar1, el1, er1, n);
  aggregate1<<<(n + 3) / 4, 256, 0, stream>>>(rowptr, csr_src, feat1b, el1, er1, b1, out, n);
}